// Round 12
// baseline (627.903 us; speedup 1.0000x reference)
//
#include <hip/hip_runtime.h>
#include <hip/hip_bf16.h>
#include <math.h>

typedef unsigned short u16;
typedef __attribute__((ext_vector_type(8))) short bf16x8;   // 8 bf16 (4 VGPRs)
typedef __attribute__((ext_vector_type(4))) float f32x4;

// Inputs may be bf16 or fp32; device flag (pe_w all-ones: first u16 0x3F80 iff
// bf16, 0x0000 iff fp32 1.0f). r1-r6 evidence: inputs are fp32, but keep flag.
__device__ __forceinline__ float ldin(const void* p, size_t i, int isbf) {
  if (isbf) return __bfloat162float(((const __hip_bfloat16*)p)[i]);
  return ((const float*)p)[i];
}
__device__ __forceinline__ float bfu(u16 u) { return __builtin_bit_cast(float, (unsigned)u << 16); }
__device__ __forceinline__ u16 f2bf(float x) {  // round-to-nearest-even
  unsigned u = __builtin_bit_cast(unsigned, x);
  unsigned r = u + 0x7FFFu + ((u >> 16) & 1u);
  return (u16)(r >> 16);
}

__device__ __forceinline__ float wave_sum(float v) {
#pragma unroll
  for (int o = 32; o > 0; o >>= 1) v += __shfl_down(v, o);
  return v;
}

__device__ __forceinline__ float block_sum(float v, float* sbuf) {
  int lane = threadIdx.x & 63;
  int wid = threadIdx.x >> 6;
#pragma unroll
  for (int o = 32; o > 0; o >>= 1) v += __shfl_down(v, o);
  __syncthreads();
  if (lane == 0) sbuf[wid] = v;
  __syncthreads();
  int nw = blockDim.x >> 6;
  if (wid == 0) {
    float r = (lane < nw) ? sbuf[lane] : 0.f;
#pragma unroll
    for (int o = 4; o > 0; o >>= 1) r += __shfl_down(r, o);
    if (lane == 0) sbuf[0] = r;
  }
  __syncthreads();
  return sbuf[0];
}

__device__ __forceinline__ float block_max(float v, float* sbuf) {
  int lane = threadIdx.x & 63;
  int wid = threadIdx.x >> 6;
#pragma unroll
  for (int o = 32; o > 0; o >>= 1) v = fmaxf(v, __shfl_down(v, o));
  __syncthreads();
  if (lane == 0) sbuf[wid] = v;
  __syncthreads();
  int nw = blockDim.x >> 6;
  if (wid == 0) {
    float r = (lane < nw) ? sbuf[lane] : -INFINITY;
#pragma unroll
    for (int o = 4; o > 0; o >>= 1) r = fmaxf(r, __shfl_down(r, o));
    if (lane == 0) sbuf[0] = r;
  }
  __syncthreads();
  return sbuf[0];
}

__global__ void flag_kernel(const void* pe_w, int* flag) {
  if (threadIdx.x == 0 && blockIdx.x == 0)
    *flag = (((const unsigned short*)pe_w)[0] != 0) ? 1 : 0;
}

// init: dtype flag + zero score buffer S (64 blocks x 256 thr x float4) + pabar
__global__ __launch_bounds__(256) void init_kernel(const void* pe_w, int* flag,
                                                   float* Sbuf, float* pabar) {
  int i = blockIdx.x * 256 + threadIdx.x;  // 16384 float4s = 65536 floats
  ((float4*)Sbuf)[i] = make_float4(0.f, 0.f, 0.f, 0.f);
  if (blockIdx.x == 0) {
    if (threadIdx.x == 0) *flag = (((const unsigned short*)pe_w)[0] != 0) ? 1 : 0;
    if (threadIdx.x < 20) pabar[threadIdx.x] = 0.f;
  }
}

// ===========================================================================
// FAST PATH kernels
// ===========================================================================

// Generalized weight convert+transpose. z -> (t = z & tmask, l = z >> lshift).
__global__ __launch_bounds__(256) void convT2(
    const void* __restrict__ S0, const void* __restrict__ S1,
    const void* __restrict__ S2, const void* __restrict__ S3,
    size_t srcStride, int K, int N, u16* __restrict__ Dh, u16* __restrict__ Dl,
    size_t layerStride, size_t tensorStride, int tmask, int lshift,
    const int* __restrict__ dflag) {
  const int isbf = *dflag;
  int z = blockIdx.z;
  int t = z & tmask, l = z >> lshift;
  const void* S = (t == 0) ? S0 : ((t == 1) ? S1 : ((t == 2) ? S2 : S3));
  size_t soff = (size_t)l * srcStride;
  size_t doff = (size_t)l * layerStride + (size_t)t * tensorStride;
  int n0 = blockIdx.x * 32, k0 = blockIdx.y * 32;
  __shared__ float tt[32][33];
  int tx = threadIdx.x & 31, ty = threadIdx.x >> 5;
#pragma unroll
  for (int j = 0; j < 4; ++j) {
    int r = ty + j * 8;
    tt[r][tx] = ldin(S, soff + (size_t)(k0 + r) * N + n0 + tx, isbf);
  }
  __syncthreads();
#pragma unroll
  for (int j = 0; j < 4; ++j) {
    int r = ty + j * 8;
    float v = tt[tx][r];
    u16 h = f2bf(v);
    u16 lo = f2bf(v - bfu(h));
    size_t o = doff + (size_t)(n0 + r) * K + k0 + tx;
    Dh[o] = h;
    Dl[o] = lo;
  }
}

// MFMA GEMM on pre-split hi/lo planes.
// mode: 0 = store fp32 C, 1 = atomicAdd (split-K via gridDim.z; bias only z==0),
//       2 = store hi/lo planes, 3 = QKV (V transposed), 4 = fp32 C AND planes,
//       5 = batched QK^T: wrow = wrowoff1 + b*128 + col0 (b = by>>1), no bias,
//           atomicAdd into C (split-K), ldc = 128.
__global__ __launch_bounds__(256) void gemm_hl(
    const u16* __restrict__ Ahp, const u16* __restrict__ Alp, int lda,
    const u16* __restrict__ Whp, const u16* __restrict__ Wlp, int ldw,
    const void* __restrict__ b0, const void* __restrict__ b1, const void* __restrict__ b2,
    size_t bo0, size_t bo1, size_t bo2, int bshift,
    float* __restrict__ C, u16* __restrict__ Chp, u16* __restrict__ Clp,
    u16* __restrict__ Vh, u16* __restrict__ Vl, int ldc,
    int K, int act, int mode, int ysplit, size_t wrowoff1,
    const int* __restrict__ dflag) {
  const int isbf = *dflag;
  __shared__ __align__(16) u16 sAh[64][72];
  __shared__ __align__(16) u16 sAl[64][72];
  __shared__ __align__(16) u16 sBh[64][72];
  __shared__ __align__(16) u16 sBl[64][72];

  int tid = threadIdx.x;
  int by = blockIdx.y;
  int row0 = by * 64, col0 = blockIdx.x * 64;
  int rsplit = (by >= ysplit);
  size_t wrow0 = (size_t)col0 + (rsplit ? wrowoff1 : 0);
  if (mode == 5) wrow0 = wrowoff1 + (size_t)(by >> 1) * 128 + col0;
  int Ksub = K / (int)gridDim.z;
  int kstart = (int)blockIdx.z * Ksub;
  int addbias = (blockIdx.z == 0) && (mode != 5);

  int wid = tid >> 6, lane = tid & 63, quad = lane >> 4, lm = lane & 15;
  int mrow = (wid & 1) * 32, ncol = (wid >> 1) * 32;

  f32x4 acc[2][2] = {};

  int sr = tid >> 2, sc = (tid & 3) * 16;

  for (int k0 = kstart; k0 < kstart + Ksub; k0 += 64) {
    const u16* p;
    p = Ahp + (size_t)(row0 + sr) * lda + k0 + sc;
    uint4 a0 = *(const uint4*)p, a1 = *(const uint4*)(p + 8);
    p = Alp + (size_t)(row0 + sr) * lda + k0 + sc;
    uint4 a2 = *(const uint4*)p, a3 = *(const uint4*)(p + 8);
    p = Whp + (wrow0 + sr) * (size_t)ldw + k0 + sc;
    uint4 w0 = *(const uint4*)p, w1 = *(const uint4*)(p + 8);
    p = Wlp + (wrow0 + sr) * (size_t)ldw + k0 + sc;
    uint4 w2 = *(const uint4*)p, w3 = *(const uint4*)(p + 8);
    __syncthreads();
    *(uint4*)&sAh[sr][sc] = a0; *(uint4*)&sAh[sr][sc + 8] = a1;
    *(uint4*)&sAl[sr][sc] = a2; *(uint4*)&sAl[sr][sc + 8] = a3;
    *(uint4*)&sBh[sr][sc] = w0; *(uint4*)&sBh[sr][sc + 8] = w1;
    *(uint4*)&sBl[sr][sc] = w2; *(uint4*)&sBl[sr][sc + 8] = w3;
    __syncthreads();
#pragma unroll
    for (int ks = 0; ks < 2; ++ks) {
      bf16x8 ah[2], al[2], wh[2], wl[2];
#pragma unroll
      for (int mi = 0; mi < 2; ++mi) {
        ah[mi] = *(const bf16x8*)&sAh[mrow + mi * 16 + lm][ks * 32 + quad * 8];
        al[mi] = *(const bf16x8*)&sAl[mrow + mi * 16 + lm][ks * 32 + quad * 8];
      }
#pragma unroll
      for (int ni = 0; ni < 2; ++ni) {
        wh[ni] = *(const bf16x8*)&sBh[ncol + ni * 16 + lm][ks * 32 + quad * 8];
        wl[ni] = *(const bf16x8*)&sBl[ncol + ni * 16 + lm][ks * 32 + quad * 8];
      }
#pragma unroll
      for (int mi = 0; mi < 2; ++mi)
#pragma unroll
        for (int ni = 0; ni < 2; ++ni) {
          acc[mi][ni] = __builtin_amdgcn_mfma_f32_16x16x32_bf16(ah[mi], wh[ni], acc[mi][ni], 0, 0, 0);
          acc[mi][ni] = __builtin_amdgcn_mfma_f32_16x16x32_bf16(al[mi], wh[ni], acc[mi][ni], 0, 0, 0);
          acc[mi][ni] = __builtin_amdgcn_mfma_f32_16x16x32_bf16(ah[mi], wl[ni], acc[mi][ni], 0, 0, 0);
        }
    }
  }
#pragma unroll
  for (int mi = 0; mi < 2; ++mi) {
#pragma unroll
    for (int ni = 0; ni < 2; ++ni) {
      int colg = col0 + ncol + ni * 16 + lm;
      float bv = 0.f;
      if (addbias) {
        const void* bp; size_t bo;
        if (rsplit) { bp = b1; bo = bo1 + colg; }
        else {
          int seg = colg >> bshift;
          bp = (seg == 0) ? b0 : ((seg == 1) ? b1 : b2);
          bo = (seg == 0) ? bo0 : ((seg == 1) ? bo1 : bo2);
          bo += (size_t)colg - ((size_t)seg << bshift);
        }
        bv = ldin(bp, bo, isbf);
      }
#pragma unroll
      for (int r = 0; r < 4; ++r) {
        int rowg = row0 + mrow + mi * 16 + quad * 4 + r;
        float v = acc[mi][ni][r] + bv;
        if (act) v = v * 0.5f * (1.f + erff(v * 0.70710678118654752f));
        if (mode == 3 && colg >= 1024) {
          int gg = rowg >> 7;
          size_t o = ((size_t)(gg * 512) + (colg - 1024)) * 128 + (rowg & 127);
          u16 hh = f2bf(v); Vh[o] = hh; Vl[o] = f2bf(v - bfu(hh));
        } else {
          size_t o = (size_t)rowg * ldc + colg;
          if (mode == 0) C[o] = v;
          else if (mode == 1 || mode == 5) atomicAdd(&C[o], v);
          else if (mode == 4) {
            C[o] = v;
            u16 hh = f2bf(v); Chp[o] = hh; Clp[o] = f2bf(v - bfu(hh));
          } else {
            u16 hh = f2bf(v); Chp[o] = hh; Clp[o] = f2bf(v - bfu(hh));
          }
        }
      }
    }
  }
}

// MFMA attention: grid 128 = (g 8, h 4, tq 4), 256 threads (4 waves).
__global__ __launch_bounds__(256) void attn_mfma(
    const u16* __restrict__ Qh, const u16* __restrict__ Ql,
    const u16* __restrict__ Vth, const u16* __restrict__ Vtl,
    u16* __restrict__ Oh, u16* __restrict__ Ol) {
  int tq = blockIdx.x & 3;
  int h = (blockIdx.x >> 2) & 3;
  int g = blockIdx.x >> 4;
  int tid = threadIdx.x;
  int w = tid >> 6, lane = tid & 63, quad = lane >> 4, lm = lane & 15;
  __shared__ float S[32][132];

  f32x4 sacc[2][2] = {};
#pragma unroll
  for (int ks = 0; ks < 4; ++ks) {
    bf16x8 qh[2], ql[2];
#pragma unroll
    for (int mi = 0; mi < 2; ++mi) {
      size_t qi = (size_t)(g * 128 + tq * 32 + mi * 16 + lm) * 1536 + h * 128 + ks * 32 + quad * 8;
      qh[mi] = *(const bf16x8*)(Qh + qi);
      ql[mi] = *(const bf16x8*)(Ql + qi);
    }
#pragma unroll
    for (int ni = 0; ni < 2; ++ni) {
      size_t kix = (size_t)(g * 128 + w * 32 + ni * 16 + lm) * 1536 + 512 + h * 128 + ks * 32 + quad * 8;
      bf16x8 kh = *(const bf16x8*)(Qh + kix);
      bf16x8 kl = *(const bf16x8*)(Ql + kix);
#pragma unroll
      for (int mi = 0; mi < 2; ++mi) {
        sacc[mi][ni] = __builtin_amdgcn_mfma_f32_16x16x32_bf16(qh[mi], kh, sacc[mi][ni], 0, 0, 0);
        sacc[mi][ni] = __builtin_amdgcn_mfma_f32_16x16x32_bf16(ql[mi], kh, sacc[mi][ni], 0, 0, 0);
        sacc[mi][ni] = __builtin_amdgcn_mfma_f32_16x16x32_bf16(qh[mi], kl, sacc[mi][ni], 0, 0, 0);
      }
    }
  }
  const float scale = 0.08838834764831845f;
#pragma unroll
  for (int mi = 0; mi < 2; ++mi)
#pragma unroll
    for (int ni = 0; ni < 2; ++ni)
#pragma unroll
      for (int r = 0; r < 4; ++r)
        S[mi * 16 + quad * 4 + r][w * 32 + ni * 16 + lm] = sacc[mi][ni][r] * scale;
  __syncthreads();

  {
    int row = tid >> 3, j = tid & 7;
    float* sp = &S[row][j * 16];
    float v[16];
    *(float4*)(v) = *(float4*)(sp);
    *(float4*)(v + 4) = *(float4*)(sp + 4);
    *(float4*)(v + 8) = *(float4*)(sp + 8);
    *(float4*)(v + 12) = *(float4*)(sp + 12);
    float mx = v[0];
#pragma unroll
    for (int i = 1; i < 16; ++i) mx = fmaxf(mx, v[i]);
    mx = fmaxf(mx, __shfl_xor(mx, 1));
    mx = fmaxf(mx, __shfl_xor(mx, 2));
    mx = fmaxf(mx, __shfl_xor(mx, 4));
    float sum = 0.f;
#pragma unroll
    for (int i = 0; i < 16; ++i) { v[i] = expf(v[i] - mx); sum += v[i]; }
    sum += __shfl_xor(sum, 1);
    sum += __shfl_xor(sum, 2);
    sum += __shfl_xor(sum, 4);
    float inv = 1.f / sum;
#pragma unroll
    for (int i = 0; i < 16; ++i) v[i] *= inv;
    *(float4*)(sp) = *(float4*)(v);
    *(float4*)(sp + 4) = *(float4*)(v + 4);
    *(float4*)(sp + 8) = *(float4*)(v + 8);
    *(float4*)(sp + 12) = *(float4*)(v + 12);
  }
  __syncthreads();

  f32x4 oacc[2][2] = {};
#pragma unroll
  for (int ks = 0; ks < 4; ++ks) {
    bf16x8 ph[2], pl[2];
#pragma unroll
    for (int mi = 0; mi < 2; ++mi) {
      float pv[8];
      const float* srow = &S[mi * 16 + lm][ks * 32 + quad * 8];
      *(float4*)(pv) = *(const float4*)srow;
      *(float4*)(pv + 4) = *(const float4*)(srow + 4);
      bf16x8 hh, ll;
#pragma unroll
      for (int i = 0; i < 8; ++i) {
        u16 hb = f2bf(pv[i]);
        hh[i] = (short)hb;
        ll[i] = (short)f2bf(pv[i] - bfu(hb));
      }
      ph[mi] = hh; pl[mi] = ll;
    }
#pragma unroll
    for (int ni = 0; ni < 2; ++ni) {
      size_t vi = (size_t)(g * 512 + h * 128 + w * 32 + ni * 16 + lm) * 128 + ks * 32 + quad * 8;
      bf16x8 vh = *(const bf16x8*)(Vth + vi);
      bf16x8 vl = *(const bf16x8*)(Vtl + vi);
#pragma unroll
      for (int mi = 0; mi < 2; ++mi) {
        oacc[mi][ni] = __builtin_amdgcn_mfma_f32_16x16x32_bf16(ph[mi], vh, oacc[mi][ni], 0, 0, 0);
        oacc[mi][ni] = __builtin_amdgcn_mfma_f32_16x16x32_bf16(pl[mi], vh, oacc[mi][ni], 0, 0, 0);
        oacc[mi][ni] = __builtin_amdgcn_mfma_f32_16x16x32_bf16(ph[mi], vl, oacc[mi][ni], 0, 0, 0);
      }
    }
  }
#pragma unroll
  for (int mi = 0; mi < 2; ++mi)
#pragma unroll
    for (int ni = 0; ni < 2; ++ni)
#pragma unroll
      for (int r = 0; r < 4; ++r) {
        int t = tq * 32 + mi * 16 + quad * 4 + r;
        int d = w * 32 + ni * 16 + lm;
        size_t o = (size_t)(g * 128 + t) * 512 + h * 128 + d;
        float val = oacc[mi][ni][r];
        u16 hb = f2bf(val);
        Oh[o] = hb;
        Ol[o] = f2bf(val - bfu(hb));
      }
}

// emb+pos LN, both encoders (1024 rows): writes fp32 x AND hi/lo planes.
__global__ __launch_bounds__(256) void emb_ln2(
    const void* __restrict__ qe, const void* __restrict__ ae, const void* __restrict__ pos,
    const void* __restrict__ w, const void* __restrict__ b,
    float* __restrict__ x, u16* __restrict__ oh, u16* __restrict__ ol,
    const int* __restrict__ dflag) {
  const int isbf = *dflag;
  const int D = 512;
  int row = blockIdx.x;
  const void* emb = (row < 512) ? qe : ae;
  int lr = row & 511, t = row & 127;
  __shared__ float sbuf[8];
  int i0 = threadIdx.x, i1 = threadIdx.x + 256;
  float v0 = ldin(emb, (size_t)lr * D + i0, isbf) + ldin(pos, (size_t)t * D + i0, isbf);
  float v1 = ldin(emb, (size_t)lr * D + i1, isbf) + ldin(pos, (size_t)t * D + i1, isbf);
  float mean = block_sum(v0 + v1, sbuf) / 512.f;
  float d0 = v0 - mean, d1 = v1 - mean;
  float var = block_sum(d0 * d0 + d1 * d1, sbuf) / 512.f;
  float inv = 1.0f / sqrtf(var + 1e-12f);
  float r0 = ldin(w, i0, isbf) * d0 * inv + ldin(b, i0, isbf);
  float r1 = ldin(w, i1, isbf) * d1 * inv + ldin(b, i1, isbf);
  size_t o0 = (size_t)row * D + i0, o1 = (size_t)row * D + i1;
  x[o0] = r0; x[o1] = r1;
  u16 h0 = f2bf(r0); oh[o0] = h0; ol[o0] = f2bf(r0 - bfu(h0));
  u16 h1 = f2bf(r1); oh[o1] = h1; ol[o1] = f2bf(r1 - bfu(h1));
}

// LN fp32 in -> optional fp32 out (in-place safe) + hi/lo planes.
__global__ __launch_bounds__(256) void ln2(
    const float* __restrict__ in, float* __restrict__ outf,
    u16* __restrict__ oh, u16* __restrict__ ol,
    const void* __restrict__ w, const void* __restrict__ b, size_t wboff,
    const int* __restrict__ dflag) {
  const int isbf = *dflag;
  const int D = 512;
  int row = blockIdx.x;
  __shared__ float sbuf[8];
  int i0 = threadIdx.x, i1 = threadIdx.x + 256;
  float v0 = in[(size_t)row * D + i0];
  float v1 = in[(size_t)row * D + i1];
  float mean = block_sum(v0 + v1, sbuf) / 512.f;
  float d0 = v0 - mean, d1 = v1 - mean;
  float var = block_sum(d0 * d0 + d1 * d1, sbuf) / 512.f;
  float inv = 1.0f / sqrtf(var + 1e-12f);
  float r0 = ldin(w, wboff + i0, isbf) * d0 * inv + ldin(b, wboff + i0, isbf);
  float r1 = ldin(w, wboff + i1, isbf) * d1 * inv + ldin(b, wboff + i1, isbf);
  size_t o0 = (size_t)row * D + i0, o1 = (size_t)row * D + i1;
  if (outf) { outf[o0] = r0; outf[o1] = r1; }
  u16 h0 = f2bf(r0); oh[o0] = h0; ol[o0] = f2bf(r0 - bfu(h0));
  u16 h1 = f2bf(r1); oh[o1] = h1; ol[o1] = f2bf(r1 - bfu(h1));
}

// proj (blocks 0..1023) + gram (blocks 1024..1048), merged.
__global__ __launch_bounds__(64) void projgram(const float* __restrict__ qkb,
                                               const void* __restrict__ ce,
                                               float* __restrict__ ck, float* __restrict__ G,
                                               const int* __restrict__ dflag) {
  const int isbf = *dflag;
  if (blockIdx.x < 1024) {
    int row = blockIdx.x;
#pragma unroll
    for (int c = 0; c < 5; ++c) {
      float acc = 0.f;
      for (int d = threadIdx.x; d < 512; d += 64)
        acc = fmaf(qkb[(size_t)row * 512 + d], ldin(ce, (size_t)c * 512 + d, isbf), acc);
      acc = wave_sum(acc);
      if (threadIdx.x == 0) ck[row * 5 + c] = acc;
    }
  } else {
    int i = blockIdx.x - 1024;
    int c = i / 5, c2 = i % 5;
    float acc = 0.f;
    for (int d = threadIdx.x; d < 512; d += 64)
      acc = fmaf(ldin(ce, (size_t)c * 512 + d, isbf), ldin(ce, (size_t)c2 * 512 + d, isbf), acc);
    acc = wave_sum(acc);
    if (threadIdx.x == 0) G[i] = acc;
  }
}

// Full relation term, t-major:
//   R[b,t,s] = sum_c qa[b,t,s,c]*(kc[b,s,c] + sum_c' G[c,c']*aq[b,s,t,c'])
//            + sum_c aq[b,s,t,c]*qc[b,t,c]
// grid 64 = (t-tile 4, s-tile 4, b 4), 256 threads. aq read s-major coalesced,
// qa read t-major coalesced, R written t-major coalesced.
__global__ __launch_bounds__(256) void prep_rel(
    const void* __restrict__ aq, const void* __restrict__ qa,
    const float* __restrict__ ck, const float* __restrict__ G,
    float* __restrict__ R, const int* __restrict__ dflag) {
  const int isbf = *dflag;
  int bx = blockIdx.x;
  int t0 = (bx & 3) * 32;
  int s0 = ((bx >> 2) & 3) * 32;
  int b = bx >> 4;
  int tid = threadIdx.x;
  __shared__ float aqs[32][164];  // [s][t*5+c], pad->4 mod 32 banks
  __shared__ float Gs[25];
  __shared__ float kcs[32][5];
  __shared__ float qcs[32][5];
  for (int i = tid; i < 5120; i += 256) {
    int s = i / 160, r = i % 160;
    aqs[s][r] = ldin(aq, ((size_t)(b * 128 + s0 + s) * 128 + t0) * 5 + r, isbf);
  }
  if (tid < 25) Gs[tid] = G[tid];
  for (int i = tid; i < 160; i += 256)
    kcs[i / 5][i % 5] = ck[(size_t)(512 + b * 128 + s0 + i / 5) * 5 + i % 5];
  for (int i = tid; i < 160; i += 256)
    qcs[i / 5][i % 5] = ck[(size_t)(b * 128 + t0 + i / 5) * 5 + i % 5];
  __syncthreads();
  for (int i = tid; i < 1024; i += 256) {
    int t = i >> 5, s = i & 31;
    size_t qoff = ((size_t)(b * 128 + t0 + t) * 128 + s0 + s) * 5;
    float r = 0.f;
#pragma unroll
    for (int c = 0; c < 5; ++c) {
      float ga = 0.f;
#pragma unroll
      for (int c2 = 0; c2 < 5; ++c2) ga = fmaf(Gs[c * 5 + c2], aqs[s][t * 5 + c2], ga);
      r = fmaf(ldin(qa, qoff + c, isbf), kcs[s][c] + ga, r);
      r = fmaf(aqs[s][t * 5 + c], qcs[t][c], r);
    }
    R[(size_t)(b * 128 + t0 + t) * 128 + s0 + s] = r;
  }
}

// Row softmax + sharpen over S+R; writes transposed PT[b][s][t].
// grid 512 = (b*128+t), 128 threads (s).
__global__ __launch_bounds__(128) void softmax_rel(
    const float* __restrict__ Sbuf, const float* __restrict__ R,
    float* __restrict__ PT) {
  int row = blockIdx.x;          // b*128 + t
  int b = row >> 7, t = row & 127;
  int s = threadIdx.x;
  __shared__ float sbuf[8];
  size_t o = (size_t)row * 128 + s;
  float sc = Sbuf[o] + R[o];
  float mx = block_max(sc, sbuf);
  float e = expf(sc - mx);
  float ssum = block_sum(e, sbuf);
  float p = e / ssum;
  float mx2 = block_max(p, sbuf);
  float e2 = expf(1000.f * (p - mx2));
  float s2 = block_sum(e2, sbuf);
  float pf = fminf(fmaxf(e2 / s2, 0.f), 1.f);
  PT[(size_t)(b * 128 + s) * 128 + t] = pf;
}

// Pbar[b,s] = sum_t PT[b,s,t]; pabar[b,c] += sum_t PT[b,s,t]*aq[b,s,t,c].
// grid 512 = (b*128+s), 64 threads (2 t's each). All reads coalesced.
__global__ __launch_bounds__(64) void pbar2(
    const float* __restrict__ PT, const void* __restrict__ aq,
    float* __restrict__ Pbar, float* __restrict__ pabar,
    const int* __restrict__ dflag) {
  const int isbf = *dflag;
  int bs = blockIdx.x;           // b*128 + s
  int b = bs >> 7;
  int lane = threadIdx.x;
  int t0 = lane * 2;
  float2 pt = *(const float2*)(PT + (size_t)bs * 128 + t0);
  size_t ao = ((size_t)bs * 128 + t0) * 5;
  float psum = pt.x + pt.y;
  float pac[5];
#pragma unroll
  for (int c = 0; c < 5; ++c)
    pac[c] = pt.x * ldin(aq, ao + c, isbf) + pt.y * ldin(aq, ao + 5 + c, isbf);
  psum = wave_sum(psum);
#pragma unroll
  for (int c = 0; c < 5; ++c) pac[c] = wave_sum(pac[c]);
  if (lane == 0) {
    Pbar[bs] = psum;
#pragma unroll
    for (int c = 0; c < 5; ++c) atomicAdd(&pabar[b * 5 + c], pac[c]);
  }
}

// mean-over-t + classifier from Pbar/pabar (coalesced k reads only).
__global__ __launch_bounds__(512) void meancls(
    const float* __restrict__ qkb, const float* __restrict__ Pbar, const float* __restrict__ pabar,
    const void* __restrict__ ce, const void* __restrict__ clsw, const void* __restrict__ clsb,
    void* __restrict__ out, const int* __restrict__ dflag) {
  const int isbf = *dflag;
  int b = blockIdx.x;
  int tid = threadIdx.x;
  __shared__ float Ps[128];
  __shared__ float pas[5];
  __shared__ float xm[512];
  __shared__ float sbuf[8];
  if (tid < 128) Ps[tid] = Pbar[b * 128 + tid];
  if (tid < 5) pas[tid] = pabar[b * 5 + tid];
  __syncthreads();
  int d = tid;
  const float* k = qkb + (size_t)(512 + b * 128) * 512 + d;
  float acc = 0.f;
  for (int s = 0; s < 128; ++s) acc = fmaf(Ps[s], k[(size_t)s * 512], acc);
#pragma unroll
  for (int c = 0; c < 5; ++c) acc = fmaf(pas[c], ldin(ce, (size_t)c * 512 + d, isbf), acc);
  acc *= (1.f / 128.f);
  xm[d] = acc;
  __syncthreads();
  for (int j = 0; j < 3; ++j) {
    float v = block_sum(xm[d] * ldin(clsw, (size_t)d * 3 + j, isbf), sbuf);
    if (d == 0) {
      float val = v + ldin(clsb, j, isbf);
      if (isbf) ((u16*)out)[b * 3 + j] = f2bf(val);
      else ((float*)out)[b * 3 + j] = val;
    }
    __syncthreads();
  }
}

// ===========================================================================
// fallback round-6 kernels (used only if ws too small for fast path)
// ===========================================================================

__global__ __launch_bounds__(256) void gemm_mfma(
    const float* __restrict__ A, const void* __restrict__ W, size_t woff,
    const void* __restrict__ bias, size_t boff,
    float* __restrict__ C, int M, int N, int K, int act, int addto,
    const int* __restrict__ dflag) {
  const int isbf = *dflag;
  __shared__ __align__(16) u16 Ah[64][40];
  __shared__ __align__(16) u16 Al[64][40];
  __shared__ __align__(16) u16 Wh[64][40];
  __shared__ __align__(16) u16 Wl[64][40];
  int tid = threadIdx.x;
  int row0 = blockIdx.y * 64, col0 = blockIdx.x * 64;
  int wid = tid >> 6, lane = tid & 63;
  int quad = lane >> 4, lm = lane & 15;
  int mrow = (wid & 1) * 32, ncol = (wid >> 1) * 32;
  f32x4 acc[2][2] = {};
  int ar = tid >> 2, akc = (tid & 3) * 8;
  int bk = tid >> 3, bn0 = (tid & 7) * 8;
  for (int k0 = 0; k0 < K; k0 += 32) {
    const float* ap = A + (size_t)(row0 + ar) * K + k0 + akc;
    float av[8];
    *(float4*)(av) = *(const float4*)ap;
    *(float4*)(av + 4) = *(const float4*)(ap + 4);
    unsigned hp[4], lp[4];
#pragma unroll
    for (int j = 0; j < 4; ++j) {
      u16 h0 = f2bf(av[2 * j]);
      u16 h1 = f2bf(av[2 * j + 1]);
      u16 l0 = f2bf(av[2 * j] - bfu(h0));
      u16 l1 = f2bf(av[2 * j + 1] - bfu(h1));
      hp[j] = (unsigned)h0 | ((unsigned)h1 << 16);
      lp[j] = (unsigned)l0 | ((unsigned)l1 << 16);
    }
    *(uint4*)&Ah[ar][akc] = make_uint4(hp[0], hp[1], hp[2], hp[3]);
    *(uint4*)&Al[ar][akc] = make_uint4(lp[0], lp[1], lp[2], lp[3]);
    float wv[8];
    size_t welem = woff + (size_t)(k0 + bk) * N + col0 + bn0;
    if (isbf) {
      const u16* wp = (const u16*)W + welem;
      uint4 raw = *(const uint4*)wp;
      wv[0] = bfu((u16)(raw.x & 0xFFFF)); wv[1] = bfu((u16)(raw.x >> 16));
      wv[2] = bfu((u16)(raw.y & 0xFFFF)); wv[3] = bfu((u16)(raw.y >> 16));
      wv[4] = bfu((u16)(raw.z & 0xFFFF)); wv[5] = bfu((u16)(raw.z >> 16));
      wv[6] = bfu((u16)(raw.w & 0xFFFF)); wv[7] = bfu((u16)(raw.w >> 16));
    } else {
      const float* wp = (const float*)W + welem;
      *(float4*)(wv) = *(const float4*)wp;
      *(float4*)(wv + 4) = *(const float4*)(wp + 4);
    }
#pragma unroll
    for (int i = 0; i < 8; ++i) {
      u16 h = f2bf(wv[i]);
      u16 l = f2bf(wv[i] - bfu(h));
      Wh[bn0 + i][bk] = h;
      Wl[bn0 + i][bk] = l;
    }
    __syncthreads();
#pragma unroll
    for (int mi = 0; mi < 2; ++mi) {
      bf16x8 ah = *(const bf16x8*)&Ah[mrow + mi * 16 + lm][quad * 8];
      bf16x8 al = *(const bf16x8*)&Al[mrow + mi * 16 + lm][quad * 8];
#pragma unroll
      for (int ni = 0; ni < 2; ++ni) {
        bf16x8 wh = *(const bf16x8*)&Wh[ncol + ni * 16 + lm][quad * 8];
        bf16x8 wl = *(const bf16x8*)&Wl[ncol + ni * 16 + lm][quad * 8];
        acc[mi][ni] = __builtin_amdgcn_mfma_f32_16x16x32_bf16(ah, wh, acc[mi][ni], 0, 0, 0);
        acc[mi][ni] = __builtin_amdgcn_mfma_f32_16x16x32_bf16(al, wh, acc[mi][ni], 0, 0, 0);
        acc[mi][ni] = __builtin_amdgcn_mfma_f32_16x16x32_bf16(ah, wl, acc[mi][ni], 0, 0, 0);
      }
    }
    __syncthreads();
  }
#pragma unroll
  for (int mi = 0; mi < 2; ++mi) {
#pragma unroll
    for (int ni = 0; ni < 2; ++ni) {
      int colg = col0 + ncol + ni * 16 + lm;
      float bv = ldin(bias, boff + colg, isbf);
#pragma unroll
      for (int r = 0; r < 4; ++r) {
        int rowg = row0 + mrow + mi * 16 + quad * 4 + r;
        float v = acc[mi][ni][r] + bv;
        if (act) v = v * 0.5f * (1.f + erff(v * 0.70710678118654752f));
        size_t o = (size_t)rowg * N + colg;
        if (addto) C[o] += v; else C[o] = v;
      }
    }
  }
}

__global__ __launch_bounds__(256) void emb_ln_kernel(const void* __restrict__ emb,
                                                     const void* __restrict__ pos,
                                                     const void* __restrict__ w,
                                                     const void* __restrict__ b,
                                                     float* __restrict__ out, int T, int D,
                                                     const int* __restrict__ dflag) {
  const int isbf = *dflag;
  int row = blockIdx.x;
  int t = row % T;
  __shared__ float sbuf[8];
  int i0 = threadIdx.x, i1 = threadIdx.x + 256;
  float v0 = ldin(emb, (size_t)row * D + i0, isbf) + ldin(pos, (size_t)t * D + i0, isbf);
  float v1 = ldin(emb, (size_t)row * D + i1, isbf) + ldin(pos, (size_t)t * D + i1, isbf);
  float mean = block_sum(v0 + v1, sbuf) / (float)D;
  float d0 = v0 - mean, d1 = v1 - mean;
  float var = block_sum(d0 * d0 + d1 * d1, sbuf) / (float)D;
  float inv = 1.0f / sqrtf(var + 1e-12f);
  out[(size_t)row * D + i0] = ldin(w, i0, isbf) * d0 * inv + ldin(b, i0, isbf);
  out[(size_t)row * D + i1] = ldin(w, i1, isbf) * d1 * inv + ldin(b, i1, isbf);
}

__global__ __launch_bounds__(256) void ln_kernel(const float* __restrict__ in, float* __restrict__ out,
                                                 const void* __restrict__ w, const void* __restrict__ b,
                                                 size_t wboff, int D, const int* __restrict__ dflag) {
  const int isbf = *dflag;
  int row = blockIdx.x;
  __shared__ float sbuf[8];
  int i0 = threadIdx.x, i1 = threadIdx.x + 256;
  float v0 = in[(size_t)row * D + i0];
  float v1 = in[(size_t)row * D + i1];
  float mean = block_sum(v0 + v1, sbuf) / (float)D;
  float d0 = v0 - mean, d1 = v1 - mean;
  float var = block_sum(d0 * d0 + d1 * d1, sbuf) / (float)D;
  float inv = 1.0f / sqrtf(var + 1e-12f);
  out[(size_t)row * D + i0] = ldin(w, wboff + i0, isbf) * d0 * inv + ldin(b, wboff + i0, isbf);
  out[(size_t)row * D + i1] = ldin(w, wboff + i1, isbf) * d1 * inv + ldin(b, wboff + i1, isbf);
}

__global__ __launch_bounds__(128) void attn_kernel(const float* __restrict__ q, const float* __restrict__ k,
                                                   const float* __restrict__ v, float* __restrict__ o,
                                                   int B, int H, int T, int dk) {
  int t = blockIdx.x % T;
  int h = (blockIdx.x / T) % H;
  int b = blockIdx.x / (T * H);
  int D = H * dk;
  int tid = threadIdx.x;
  __shared__ float qs[128];
  __shared__ float ps[128];
  __shared__ float sbuf[8];
  qs[tid] = q[(size_t)(b * T + t) * D + h * dk + tid];
  __syncthreads();
  const float* krow = k + (size_t)(b * T + tid) * D + h * dk;
  float sc = 0.f;
#pragma unroll 8
  for (int d = 0; d < 128; ++d) sc = fmaf(qs[d], krow[d], sc);
  sc *= 0.08838834764831845f;
  float mx = block_max(sc, sbuf);
  float e = expf(sc - mx);
  float s = block_sum(e, sbuf);
  ps[tid] = e / s;
  __syncthreads();
  float acc = 0.f;
  for (int s2 = 0; s2 < 128; ++s2)
    acc = fmaf(ps[s2], v[(size_t)(b * T + s2) * D + h * dk + tid], acc);
  o[(size_t)(b * T + t) * D + h * dk + tid] = acc;
}

__global__ __launch_bounds__(64) void proj_ce_kernel(const float* __restrict__ q,
                                                     const void* __restrict__ ce,
                                                     float* __restrict__ out, int D, int NC,
                                                     const int* __restrict__ dflag) {
  const int isbf = *dflag;
  int row = blockIdx.x;
  for (int c = 0; c < NC; ++c) {
    float acc = 0.f;
    for (int d = threadIdx.x; d < D; d += 64)
      acc = fmaf(q[(size_t)row * D + d], ldin(ce, (size_t)c * D + d, isbf), acc);
    acc = wave_sum(acc);
    if (threadIdx.x == 0) out[row * NC + c] = acc;
  }
}

__global__ __launch_bounds__(64) void gram_kernel(const void* __restrict__ ce,
                                                  float* __restrict__ G, int D, int NC,
                                                  const int* __restrict__ dflag) {
  const int isbf = *dflag;
  int c = blockIdx.x / NC, c2 = blockIdx.x % NC;
  float acc = 0.f;
  for (int d = threadIdx.x; d < D; d += 64)
    acc = fmaf(ldin(ce, (size_t)c * D + d, isbf), ldin(ce, (size_t)c2 * D + d, isbf), acc);
  acc = wave_sum(acc);
  if (threadIdx.x == 0) G[blockIdx.x] = acc;
}

__global__ __launch_bounds__(128) void sim_scores_kernel(
    const float* __restrict__ q, const float* __restrict__ k, const void* __restrict__ qa,
    const void* __restrict__ aq, const float* __restrict__ qc, const float* __restrict__ kc,
    const float* __restrict__ G, float* __restrict__ p_out, float* __restrict__ pa_out,
    int B, int T1, int T2, int D, int NC, const int* __restrict__ dflag) {
  const int isbf = *dflag;
  int t = blockIdx.x % T1;
  int b = blockIdx.x / T1;
  int s = threadIdx.x;
  __shared__ float qs[512];
  __shared__ float Gs[25];
  __shared__ float qcs[5];
  __shared__ float sbuf[8];
  for (int i = threadIdx.x; i < D; i += 128) qs[i] = q[(size_t)(b * T1 + t) * D + i];
  if (threadIdx.x < NC * NC) Gs[threadIdx.x] = G[threadIdx.x];
  if (threadIdx.x < NC) qcs[threadIdx.x] = qc[(b * T1 + t) * NC + threadIdx.x];
  __syncthreads();
  const float* krow = k + (size_t)(b * T2 + s) * D;
  float sc = 0.f;
#pragma unroll 8
  for (int d = 0; d < 512; ++d) sc = fmaf(qs[d], krow[d], sc);
  float qav[5], aqv[5];
#pragma unroll
  for (int c = 0; c < 5; ++c) {
    qav[c] = ldin(qa, (size_t)((b * T1 + t) * T2 + s) * NC + c, isbf);
    aqv[c] = ldin(aq, (size_t)((b * T2 + s) * T1 + t) * NC + c, isbf);
  }
#pragma unroll
  for (int c = 0; c < 5; ++c) {
    sc = fmaf(aqv[c], qcs[c], sc);
    sc = fmaf(qav[c], kc[(b * T2 + s) * NC + c], sc);
#pragma unroll
    for (int c2 = 0; c2 < 5; ++c2) sc = fmaf(qav[c] * Gs[c * 5 + c2], aqv[c2], sc);
  }
  float mx = block_max(sc, sbuf);
  float e = expf(sc - mx);
  float ssum = block_sum(e, sbuf);
  float p = e / ssum;
  float mx2 = block_max(p, sbuf);
  float e2 = expf(1000.f * (p - mx2));
  float s2 = block_sum(e2, sbuf);
  float pf = fminf(fmaxf(e2 / s2, 0.f), 1.f);
  p_out[(size_t)(b * T1 + t) * T2 + s] = pf;
#pragma unroll
  for (int c = 0; c < 5; ++c) {
    float pc = block_sum(pf * aqv[c], sbuf);
    if (threadIdx.x == 0) pa_out[(b * T1 + t) * NC + c] = pc;
  }
}

__global__ __launch_bounds__(512) void sim_x_kernel(const float* __restrict__ p, const float* __restrict__ k,
                                                    const float* __restrict__ pa,
                                                    const void* __restrict__ ce,
                                                    float* __restrict__ x, int B, int T1, int T2, int D, int NC,
                                                    const int* __restrict__ dflag) {
  const int isbf = *dflag;
  int t = blockIdx.x % T1;
  int b = blockIdx.x / T1;
  int d = threadIdx.x;
  __shared__ float ps[128];
  __shared__ float pav[5];
  if (threadIdx.x < T2) ps[threadIdx.x] = p[(size_t)(b * T1 + t) * T2 + threadIdx.x];
  if (threadIdx.x < NC) pav[threadIdx.x] = pa[(b * T1 + t) * NC + threadIdx.x];
  __syncthreads();
  float acc = 0.f;
  for (int s = 0; s < 128; ++s) acc = fmaf(ps[s], k[(size_t)(b * T2 + s) * D + d], acc);
#pragma unroll
  for (int c = 0; c < 5; ++c) acc = fmaf(pav[c], ldin(ce, (size_t)c * D + d, isbf), acc);
  x[(size_t)(b * T1 + t) * D + d] = acc;
}

__global__ __launch_bounds__(512) void mean_kernel(const float* __restrict__ x, float* __restrict__ xm,
                                                   int T, int D) {
  int b = blockIdx.x;
  int d = threadIdx.x;
  float acc = 0.f;
  for (int t = 0; t < T; ++t) acc += x[(size_t)(b * T + t) * D + d];
  xm[(size_t)b * D + d] = acc / (float)T;
}

__global__ __launch_bounds__(64) void cls_kernel(const float* __restrict__ xm,
                                                 const void* __restrict__ w,
                                                 const void* __restrict__ bias,
                                                 void* __restrict__ out, int D, int NO,
                                                 const int* __restrict__ dflag) {
  const int isbf = *dflag;
  int j = blockIdx.x % NO;
  int b = blockIdx.x / NO;
  float acc = 0.f;
  for (int d = threadIdx.x; d < D; d += 64)
    acc = fmaf(xm[(size_t)b * D + d], ldin(w, (size_t)d * NO + j, isbf), acc);
  acc = wave_sum(acc);
  if (threadIdx.x == 0) {
    float val = acc + ldin(bias, j, isbf);
    if (isbf) ((__hip_bfloat16*)out)[b * NO + j] = __float2bfloat16(val);
    else ((float*)out)[b * NO + j] = val;
  }
}

// ===========================================================================
extern "C" void kernel_launch(void* const* d_in, const int* in_sizes, int n_in,
                              void* d_out, int out_size, void* d_ws, size_t ws_size,
                              hipStream_t stream) {
  const int B = 4, T = 128, D = 512, H = 4, NL = 4, DFF = 2048, NC = 5;
  const void *q_emb = d_in[0], *a_emb = d_in[1], *qa = d_in[2], *aqr = d_in[3],
             *ce = d_in[4], *pos = d_in[5], *pe_w = d_in[6], *pe_b = d_in[7],
             *Wq = d_in[8], *bq = d_in[9], *Wk = d_in[10], *bk = d_in[11],
             *Wv = d_in[12], *bv = d_in[13], *Wo = d_in[14], *bo = d_in[15],
             *ff1w = d_in[16], *ff1b = d_in[17], *ff2w = d_in[18], *ff2b = d_in[19],
             *lnin_w = d_in[20], *lnin_b = d_in[21], *lnout_w = d_in[22], *lnout_b = d_in[23],
             *simWq = d_in[24], *simbq = d_in[25], *simWk = d_in[26], *simbk = d_in[27],
             *clsw = d_in[28], *clsb = d_in[29];

  const size_t REQ = 83000000ull;  // poison-fill showed ws ~268 MB; fallback if smaller
  if (ws_size >= REQ) {
    // -------- FAST PATH --------
    char* base = (char*)d_ws;
    float* x = (float*)(base + 0);
    u16* xch = (u16*)(base + 2097152);
    u16* xcl = (u16*)(base + 3145728);
    u16* qkvh = (u16*)(base + 4194304);
    u16* qkvl = (u16*)(base + 7340032);
    u16* ffch = (u16*)(base + 10485760);
    u16* ffcl = (u16*)(base + 14680064);
    u16* Vth = (u16*)(base + 18874368);
    u16* Vtl = (u16*)(base + 19922944);
    float* qkb = (float*)(base + 20971520);        // [1024][512] fp32 sim q|k
    u16* qsh = (u16*)(base + 23068672);            // sim q|k hi plane [1024][512]
    u16* qsl = (u16*)(base + 24117248);            // lo
    float* ck = (float*)(base + 25165824);         // [1024][5]
    float* Gbuf = (float*)(base + 25186304);       // 25
    float* Pbar = (float*)(base + 25190400);       // [4][128]
    float* pabar = (float*)(base + 25192448);      // [4][5]
    int* dflag = (int*)(base + 25196544);
    u16* wh = (u16*)(base + 26214400);             // 13,107,200 elems
    u16* wl = (u16*)(base + 52428800);
    float* Sbuf = (float*)(base + 79691776);       // [4][128][128] scores (256 KB)
    float* R = (float*)(base + 79953920);          // [4][128][128] relation (256 KB)
    float* PT = (float*)(base + 80216064);         // [4][128][128] sharpened P^T (256 KB)
    // wAll layout per layer l (base l*3145728): QKVO T [2048][512] | FF1 T | FF2 T [512][2048]
    // sim at +12582912: [1024][512]

    init_kernel<<<64, 256, 0, stream>>>(pe_w, dflag, Sbuf, pabar);
    convT2<<<dim3(16, 16, 16), 256, 0, stream>>>(Wq, Wk, Wv, Wo, 262144, 512, 512,
                                                 wh, wl, 3145728, 262144, 3, 2, dflag);
    convT2<<<dim3(64, 16, 4), 256, 0, stream>>>(ff1w, ff1w, ff1w, ff1w, 1048576, 512, 2048,
                                                wh + 1048576, wl + 1048576, 3145728, 0, 0, 0, dflag);
    convT2<<<dim3(16, 64, 4), 256, 0, stream>>>(ff2w, ff2w, ff2w, ff2w, 1048576, 2048, 512,
                                                wh + 2097152, wl + 2097152, 3145728, 0, 0, 0, dflag);
    convT2<<<dim3(16, 16, 2), 256, 0, stream>>>(simWq, simWk, simWk, simWk, 0, 512, 512,
                                                wh + 12582912, wl + 12582912, 0, 262144, 1, 1, dflag);

    emb_ln2<<<1024, 256, 0, stream>>>(q_emb, a_emb, pos, pe_w, pe_b, x, xch, xcl, dflag);

    for (int l = 0; l < NL; ++l) {
      size_t wbase = (size_t)l * 3145728, bD = (size_t)l * D;
      gemm_hl<<<dim3(24, 16, 1), 256, 0, stream>>>(xch, xcl, 512, wh + wbase, wl + wbase, 512,
                                                   bq, bk, bv, bD, bD, bD, 9,
                                                   nullptr, qkvh, qkvl, Vth, Vtl, 1536,
                                                   512, 0, 3, 9999, 0, dflag);
      attn_mfma<<<128, 256, 0, stream>>>(qkvh, qkvl, Vth, Vtl, xch, xcl);
      gemm_hl<<<dim3(8, 16, 2), 256, 0, stream>>>(xch, xcl, 512, wh + wbase + 786432,
                                                  wl + wbase + 786432, 512,
                                                  bo, bo, bo, bD, bD, bD, 9,
                                                  x, nullptr, nullptr, nullptr, nullptr, 512,
                                                  512, 0, 1, 9999, 0, dflag);
      ln2<<<1024, 256, 0, stream>>>(x, nullptr, xch, xcl, lnin_w, lnin_b, bD, dflag);
      gemm_hl<<<dim3(32, 16, 1), 256, 0, stream>>>(xch, xcl, 512, wh + wbase + 1048576,
                                                   wl + wbase + 1048576, 512,
                                                   ff1b, ff1b, ff1b,
                                                   (size_t)l * DFF, (size_t)l * DFF, (size_t)l * DFF, 11,
                                                   nullptr, ffch, ffcl, nullptr, nullptr, 2048,
                                                   512, 1, 2, 9999, 0, dflag);
      gemm_hl<<<dim3(8, 16, 2), 256, 0, stream>>>(ffch, ffcl, 2048, wh + wbase + 2097152,
                                                  wl + wbase + 2097152, 2048,
                                                  ff2b, ff2b, ff2b, bD, bD, bD, 9,
                                                  x, nullptr, nullptr, nullptr, nullptr, 512,
                                                  2048, 0, 1, 9999, 0, dflag);
      ln2<<<1024, 256, 0, stream>>>(x, x, xch, xcl, lnout_w, lnout_b, bD, dflag);
    }

    // Sim head
    gemm_hl<<<dim3(8, 16, 1), 256, 0, stream>>>(xch, xcl, 512, wh + 12582912, wl + 12582912, 512,
                                                simbq, simbk, simbk, 0, 0, 0, 9,
                                                qkb, qsh, qsl, nullptr, nullptr, 512,
                                                512, 0, 4, 8, 512, dflag);
    projgram<<<1049, 64, 0, stream>>>(qkb, ce, ck, Gbuf, dflag);
    prep_rel<<<64, 256, 0, stream>>>(aqr, qa, ck, Gbuf, R, dflag);
    // S = q @ k^T (batched over b, split-K z=4, atomicAdd into zeroed Sbuf)
    gemm_hl<<<dim3(2, 8, 4), 256, 0, stream>>>(qsh, qsl, 512, qsh, qsl, 512,
                                               nullptr, nullptr, nullptr, 0, 0, 0, 9,
                                               Sbuf, nullptr, nullptr, nullptr, nullptr, 128,
                                               512, 0, 5, 9999, 512, dflag);
    softmax_rel<<<512, 128, 0, stream>>>(Sbuf, R, PT);
    pbar2<<<512, 64, 0, stream>>>(PT, aqr, Pbar, pabar, dflag);
    meancls<<<4, 512, 0, stream>>>(qkb, Pbar, pabar, ce, clsw, clsb, d_out, dflag);
    return;
  }

  // -------- FALLBACK: round-6 passing path --------
  float* ws = (float*)d_ws;
  const size_t S = (size_t)512 * 512;
  float* qe = ws;
  float* ae = ws + S;
  float* hb = ws + 2 * S;
  float* rb = ws + 3 * S;
  float* qb = rb;
  float* kb = rb + S;
  float* vb = rb + 2 * S;
  float* ob = rb + 3 * S;
  float* ffb = rb;
  float* pbuf = rb + 2 * S;
  float* pabuf = pbuf + 65536;
  float* qcbuf = pabuf + 2560;
  float* kcbuf = qcbuf + 2560;
  float* Gbuf = kcbuf + 2560;
  float* xmean = Gbuf + 32;
  float* xsim = rb + 3 * S;
  int* dflag = (int*)(ws + 7 * S);

  const int M = B * T;
  dim3 gD(8, 8), gF1(32, 8), gF2(8, 8);

  flag_kernel<<<1, 64, 0, stream>>>(pe_w, dflag);
  for (int e = 0; e < 2; ++e) {
    float* x = (e == 0) ? qe : ae;
    const void* emb = (e == 0) ? q_emb : a_emb;
    emb_ln_kernel<<<M, 256, 0, stream>>>(emb, pos, pe_w, pe_b, x, T, D, dflag);
    for (int l = 0; l < NL; ++l) {
      size_t wDD = (size_t)l * D * D, bD = (size_t)l * D;
      gemm_mfma<<<gD, 256, 0, stream>>>(x, Wq, wDD, bq, bD, qb, M, D, D, 0, 0, dflag);
      gemm_mfma<<<gD, 256, 0, stream>>>(x, Wk, wDD, bk, bD, kb, M, D, D, 0, 0, dflag);
      gemm_mfma<<<gD, 256, 0, stream>>>(x, Wv, wDD, bv, bD, vb, M, D, D, 0, 0, dflag);
      attn_kernel<<<B * H * T, 128, 0, stream>>>(qb, kb, vb, ob, B, H, T, D / H);
      gemm_mfma<<<gD, 256, 0, stream>>>(ob, Wo, wDD, bo, bD, x, M, D, D, 0, 1, dflag);
      ln_kernel<<<M, 256, 0, stream>>>(x, hb, lnin_w, lnin_b, bD, D, dflag);
      gemm_mfma<<<gF1, 256, 0, stream>>>(hb, ff1w, (size_t)l * D * DFF, ff1b, (size_t)l * DFF,
                                         ffb, M, DFF, D, 1, 0, dflag);
      gemm_mfma<<<gF2, 256, 0, stream>>>(ffb, ff2w, (size_t)l * DFF * D, ff2b, bD,
                                         x, M, D, DFF, 0, 1, dflag);
      ln_kernel<<<M, 256, 0, stream>>>(x, x, lnout_w, lnout_b, bD, D, dflag);
    }
  }
  gemm_mfma<<<gD, 256, 0, stream>>>(qe, simWq, 0, simbq, 0, qb, M, D, D, 0, 0, dflag);
  gemm_mfma<<<gD, 256, 0, stream>>>(ae, simWk, 0, simbk, 0, kb, M, D, D, 0, 0, dflag);
  proj_ce_kernel<<<M, 64, 0, stream>>>(qb, ce, qcbuf, D, NC, dflag);
  proj_ce_kernel<<<M, 64, 0, stream>>>(kb, ce, kcbuf, D, NC, dflag);
  gram_kernel<<<NC * NC, 64, 0, stream>>>(ce, Gbuf, D, NC, dflag);
  sim_scores_kernel<<<B * T, 128, 0, stream>>>(qb, kb, qa, aqr, qcbuf, kcbuf, Gbuf, pbuf, pabuf,
                                               B, T, T, D, NC, dflag);
  sim_x_kernel<<<B * T, 512, 0, stream>>>(pbuf, kb, pabuf, ce, xsim, B, T, T, D, NC, dflag);
  mean_kernel<<<B, 512, 0, stream>>>(xsim, xmean, T, D);
  cls_kernel<<<B * 3, 64, 0, stream>>>(xmean, clsw, clsb, d_out, D, 3, dflag);
}

// Round 13
// 593.485 us; speedup vs baseline: 1.0580x; 1.0580x over previous
//
#include <hip/hip_runtime.h>
#include <hip/hip_bf16.h>
#include <math.h>

typedef unsigned short u16;
typedef __attribute__((ext_vector_type(8))) short bf16x8;   // 8 bf16 (4 VGPRs)
typedef __attribute__((ext_vector_type(4))) float f32x4;

// Inputs may be bf16 or fp32; device flag (pe_w all-ones: first u16 0x3F80 iff
// bf16, 0x0000 iff fp32 1.0f). r1-r6 evidence: inputs are fp32, but keep flag.
__device__ __forceinline__ float ldin(const void* p, size_t i, int isbf) {
  if (isbf) return __bfloat162float(((const __hip_bfloat16*)p)[i]);
  return ((const float*)p)[i];
}
__device__ __forceinline__ float bfu(u16 u) { return __builtin_bit_cast(float, (unsigned)u << 16); }
__device__ __forceinline__ u16 f2bf(float x) {  // round-to-nearest-even
  unsigned u = __builtin_bit_cast(unsigned, x);
  unsigned r = u + 0x7FFFu + ((u >> 16) & 1u);
  return (u16)(r >> 16);
}

__device__ __forceinline__ float wave_sum(float v) {
#pragma unroll
  for (int o = 32; o > 0; o >>= 1) v += __shfl_down(v, o);
  return v;
}

__device__ __forceinline__ float block_sum(float v, float* sbuf) {
  int lane = threadIdx.x & 63;
  int wid = threadIdx.x >> 6;
#pragma unroll
  for (int o = 32; o > 0; o >>= 1) v += __shfl_down(v, o);
  __syncthreads();
  if (lane == 0) sbuf[wid] = v;
  __syncthreads();
  int nw = blockDim.x >> 6;
  if (wid == 0) {
    float r = (lane < nw) ? sbuf[lane] : 0.f;
#pragma unroll
    for (int o = 4; o > 0; o >>= 1) r += __shfl_down(r, o);
    if (lane == 0) sbuf[0] = r;
  }
  __syncthreads();
  return sbuf[0];
}

__device__ __forceinline__ float block_max(float v, float* sbuf) {
  int lane = threadIdx.x & 63;
  int wid = threadIdx.x >> 6;
#pragma unroll
  for (int o = 32; o > 0; o >>= 1) v = fmaxf(v, __shfl_down(v, o));
  __syncthreads();
  if (lane == 0) sbuf[wid] = v;
  __syncthreads();
  int nw = blockDim.x >> 6;
  if (wid == 0) {
    float r = (lane < nw) ? sbuf[lane] : -INFINITY;
#pragma unroll
    for (int o = 4; o > 0; o >>= 1) r = fmaxf(r, __shfl_down(r, o));
    if (lane == 0) sbuf[0] = r;
  }
  __syncthreads();
  return sbuf[0];
}

__global__ void flag_kernel(const void* pe_w, int* flag) {
  if (threadIdx.x == 0 && blockIdx.x == 0)
    *flag = (((const unsigned short*)pe_w)[0] != 0) ? 1 : 0;
}

// ===========================================================================
// FAST PATH kernels
// ===========================================================================

// ALL weight convert+transpose in one launch. grid (16,16,50); z decodes:
//   [0,16)  QKVO: t=z&3, l=z>>2           src [512][512]  -> l*3145728 + t*262144
//   [16,32) FF1:  l=(z-16)>>2, xg=(z-16)&3 src [512][2048] -> l*3145728 + 1048576
//   [32,48) FF2:  l=(z-32)>>2, yg=(z-32)&3 src [2048][512] -> l*3145728 + 2097152
//   48,49   simWq/simWk [512][512]         -> 12582912 + (z-48)*262144
__global__ __launch_bounds__(256) void convT_all(
    const void* __restrict__ Wq, const void* __restrict__ Wk,
    const void* __restrict__ Wv, const void* __restrict__ Wo,
    const void* __restrict__ ff1w, const void* __restrict__ ff2w,
    const void* __restrict__ simWq, const void* __restrict__ simWk,
    u16* __restrict__ Dh, u16* __restrict__ Dl, const int* __restrict__ dflag) {
  const int isbf = *dflag;
  int z = blockIdx.z, x = blockIdx.x, y = blockIdx.y;
  const void* S;
  size_t soff, doff;
  int K, N, n0, k0;
  if (z < 16) {
    int t = z & 3, l = z >> 2;
    S = (t == 0) ? Wq : ((t == 1) ? Wk : ((t == 2) ? Wv : Wo));
    soff = (size_t)l * 262144; K = 512; N = 512;
    doff = (size_t)l * 3145728 + (size_t)t * 262144;
    n0 = x * 32; k0 = y * 32;
  } else if (z < 32) {
    int idx = z - 16, l = idx >> 2, xg = idx & 3;
    S = ff1w; soff = (size_t)l * 1048576; K = 512; N = 2048;
    doff = (size_t)l * 3145728 + 1048576;
    n0 = (xg * 16 + x) * 32; k0 = y * 32;
  } else if (z < 48) {
    int idx = z - 32, l = idx >> 2, yg = idx & 3;
    S = ff2w; soff = (size_t)l * 1048576; K = 2048; N = 512;
    doff = (size_t)l * 3145728 + 2097152;
    n0 = x * 32; k0 = (yg * 16 + y) * 32;
  } else {
    S = (z == 48) ? simWq : simWk;
    soff = 0; K = 512; N = 512;
    doff = 12582912 + (size_t)(z - 48) * 262144;
    n0 = x * 32; k0 = y * 32;
  }
  __shared__ float tt[32][33];
  int tx = threadIdx.x & 31, ty = threadIdx.x >> 5;
#pragma unroll
  for (int j = 0; j < 4; ++j) {
    int r = ty + j * 8;
    tt[r][tx] = ldin(S, soff + (size_t)(k0 + r) * N + n0 + tx, isbf);
  }
  __syncthreads();
#pragma unroll
  for (int j = 0; j < 4; ++j) {
    int r = ty + j * 8;
    float v = tt[tx][r];
    u16 h = f2bf(v);
    u16 lo = f2bf(v - bfu(h));
    size_t o = doff + (size_t)(n0 + r) * K + k0 + tx;
    Dh[o] = h;
    Dl[o] = lo;
  }
}

// MFMA GEMM on pre-split hi/lo planes.
// mode: 0 = store fp32 C, 1 = atomicAdd (split-K via gridDim.z; bias only z==0),
//       2 = store hi/lo planes, 3 = QKV (V transposed), 4 = fp32 C AND planes,
//       6 = batched QK^T store: wrow = wrowoff1 + b*128 + col0 (b = by>>1),
//           no bias, plain store into C, ldc = 128.
__global__ __launch_bounds__(256) void gemm_hl(
    const u16* __restrict__ Ahp, const u16* __restrict__ Alp, int lda,
    const u16* __restrict__ Whp, const u16* __restrict__ Wlp, int ldw,
    const void* __restrict__ b0, const void* __restrict__ b1, const void* __restrict__ b2,
    size_t bo0, size_t bo1, size_t bo2, int bshift,
    float* __restrict__ C, u16* __restrict__ Chp, u16* __restrict__ Clp,
    u16* __restrict__ Vh, u16* __restrict__ Vl, int ldc,
    int K, int act, int mode, int ysplit, size_t wrowoff1,
    const int* __restrict__ dflag) {
  const int isbf = *dflag;
  __shared__ __align__(16) u16 sAh[64][72];
  __shared__ __align__(16) u16 sAl[64][72];
  __shared__ __align__(16) u16 sBh[64][72];
  __shared__ __align__(16) u16 sBl[64][72];

  int tid = threadIdx.x;
  int by = blockIdx.y;
  int row0 = by * 64, col0 = blockIdx.x * 64;
  int rsplit = (by >= ysplit);
  size_t wrow0 = (size_t)col0 + (rsplit ? wrowoff1 : 0);
  if (mode == 6) wrow0 = wrowoff1 + (size_t)(by >> 1) * 128 + col0;
  int Ksub = K / (int)gridDim.z;
  int kstart = (int)blockIdx.z * Ksub;
  int addbias = (blockIdx.z == 0) && (mode != 6);

  int wid = tid >> 6, lane = tid & 63, quad = lane >> 4, lm = lane & 15;
  int mrow = (wid & 1) * 32, ncol = (wid >> 1) * 32;

  f32x4 acc[2][2] = {};

  int sr = tid >> 2, sc = (tid & 3) * 16;

  for (int k0 = kstart; k0 < kstart + Ksub; k0 += 64) {
    const u16* p;
    p = Ahp + (size_t)(row0 + sr) * lda + k0 + sc;
    uint4 a0 = *(const uint4*)p, a1 = *(const uint4*)(p + 8);
    p = Alp + (size_t)(row0 + sr) * lda + k0 + sc;
    uint4 a2 = *(const uint4*)p, a3 = *(const uint4*)(p + 8);
    p = Whp + (wrow0 + sr) * (size_t)ldw + k0 + sc;
    uint4 w0 = *(const uint4*)p, w1 = *(const uint4*)(p + 8);
    p = Wlp + (wrow0 + sr) * (size_t)ldw + k0 + sc;
    uint4 w2 = *(const uint4*)p, w3 = *(const uint4*)(p + 8);
    __syncthreads();
    *(uint4*)&sAh[sr][sc] = a0; *(uint4*)&sAh[sr][sc + 8] = a1;
    *(uint4*)&sAl[sr][sc] = a2; *(uint4*)&sAl[sr][sc + 8] = a3;
    *(uint4*)&sBh[sr][sc] = w0; *(uint4*)&sBh[sr][sc + 8] = w1;
    *(uint4*)&sBl[sr][sc] = w2; *(uint4*)&sBl[sr][sc + 8] = w3;
    __syncthreads();
#pragma unroll
    for (int ks = 0; ks < 2; ++ks) {
      bf16x8 ah[2], al[2], wh[2], wl[2];
#pragma unroll
      for (int mi = 0; mi < 2; ++mi) {
        ah[mi] = *(const bf16x8*)&sAh[mrow + mi * 16 + lm][ks * 32 + quad * 8];
        al[mi] = *(const bf16x8*)&sAl[mrow + mi * 16 + lm][ks * 32 + quad * 8];
      }
#pragma unroll
      for (int ni = 0; ni < 2; ++ni) {
        wh[ni] = *(const bf16x8*)&sBh[ncol + ni * 16 + lm][ks * 32 + quad * 8];
        wl[ni] = *(const bf16x8*)&sBl[ncol + ni * 16 + lm][ks * 32 + quad * 8];
      }
#pragma unroll
      for (int mi = 0; mi < 2; ++mi)
#pragma unroll
        for (int ni = 0; ni < 2; ++ni) {
          acc[mi][ni] = __builtin_amdgcn_mfma_f32_16x16x32_bf16(ah[mi], wh[ni], acc[mi][ni], 0, 0, 0);
          acc[mi][ni] = __builtin_amdgcn_mfma_f32_16x16x32_bf16(al[mi], wh[ni], acc[mi][ni], 0, 0, 0);
          acc[mi][ni] = __builtin_amdgcn_mfma_f32_16x16x32_bf16(ah[mi], wl[ni], acc[mi][ni], 0, 0, 0);
        }
    }
  }
#pragma unroll
  for (int mi = 0; mi < 2; ++mi) {
#pragma unroll
    for (int ni = 0; ni < 2; ++ni) {
      int colg = col0 + ncol + ni * 16 + lm;
      float bv = 0.f;
      if (addbias) {
        const void* bp; size_t bo;
        if (rsplit) { bp = b1; bo = bo1 + colg; }
        else {
          int seg = colg >> bshift;
          bp = (seg == 0) ? b0 : ((seg == 1) ? b1 : b2);
          bo = (seg == 0) ? bo0 : ((seg == 1) ? bo1 : bo2);
          bo += (size_t)colg - ((size_t)seg << bshift);
        }
        bv = ldin(bp, bo, isbf);
      }
#pragma unroll
      for (int r = 0; r < 4; ++r) {
        int rowg = row0 + mrow + mi * 16 + quad * 4 + r;
        float v = acc[mi][ni][r] + bv;
        if (act) v = v * 0.5f * (1.f + erff(v * 0.70710678118654752f));
        if (mode == 3 && colg >= 1024) {
          int gg = rowg >> 7;
          size_t o = ((size_t)(gg * 512) + (colg - 1024)) * 128 + (rowg & 127);
          u16 hh = f2bf(v); Vh[o] = hh; Vl[o] = f2bf(v - bfu(hh));
        } else {
          size_t o = (size_t)rowg * ldc + colg;
          if (mode == 0 || mode == 6) C[o] = v;
          else if (mode == 1) atomicAdd(&C[o], v);
          else if (mode == 4) {
            C[o] = v;
            u16 hh = f2bf(v); Chp[o] = hh; Clp[o] = f2bf(v - bfu(hh));
          } else {
            u16 hh = f2bf(v); Chp[o] = hh; Clp[o] = f2bf(v - bfu(hh));
          }
        }
      }
    }
  }
}

// MFMA attention: grid 128 = (g 8, h 4, tq 4), 256 threads (4 waves).
__global__ __launch_bounds__(256) void attn_mfma(
    const u16* __restrict__ Qh, const u16* __restrict__ Ql,
    const u16* __restrict__ Vth, const u16* __restrict__ Vtl,
    u16* __restrict__ Oh, u16* __restrict__ Ol) {
  int tq = blockIdx.x & 3;
  int h = (blockIdx.x >> 2) & 3;
  int g = blockIdx.x >> 4;
  int tid = threadIdx.x;
  int w = tid >> 6, lane = tid & 63, quad = lane >> 4, lm = lane & 15;
  __shared__ float S[32][132];

  f32x4 sacc[2][2] = {};
#pragma unroll
  for (int ks = 0; ks < 4; ++ks) {
    bf16x8 qh[2], ql[2];
#pragma unroll
    for (int mi = 0; mi < 2; ++mi) {
      size_t qi = (size_t)(g * 128 + tq * 32 + mi * 16 + lm) * 1536 + h * 128 + ks * 32 + quad * 8;
      qh[mi] = *(const bf16x8*)(Qh + qi);
      ql[mi] = *(const bf16x8*)(Ql + qi);
    }
#pragma unroll
    for (int ni = 0; ni < 2; ++ni) {
      size_t kix = (size_t)(g * 128 + w * 32 + ni * 16 + lm) * 1536 + 512 + h * 128 + ks * 32 + quad * 8;
      bf16x8 kh = *(const bf16x8*)(Qh + kix);
      bf16x8 kl = *(const bf16x8*)(Ql + kix);
#pragma unroll
      for (int mi = 0; mi < 2; ++mi) {
        sacc[mi][ni] = __builtin_amdgcn_mfma_f32_16x16x32_bf16(qh[mi], kh, sacc[mi][ni], 0, 0, 0);
        sacc[mi][ni] = __builtin_amdgcn_mfma_f32_16x16x32_bf16(ql[mi], kh, sacc[mi][ni], 0, 0, 0);
        sacc[mi][ni] = __builtin_amdgcn_mfma_f32_16x16x32_bf16(qh[mi], kl, sacc[mi][ni], 0, 0, 0);
      }
    }
  }
  const float scale = 0.08838834764831845f;
#pragma unroll
  for (int mi = 0; mi < 2; ++mi)
#pragma unroll
    for (int ni = 0; ni < 2; ++ni)
#pragma unroll
      for (int r = 0; r < 4; ++r)
        S[mi * 16 + quad * 4 + r][w * 32 + ni * 16 + lm] = sacc[mi][ni][r] * scale;
  __syncthreads();

  {
    int row = tid >> 3, j = tid & 7;
    float* sp = &S[row][j * 16];
    float v[16];
    *(float4*)(v) = *(float4*)(sp);
    *(float4*)(v + 4) = *(float4*)(sp + 4);
    *(float4*)(v + 8) = *(float4*)(sp + 8);
    *(float4*)(v + 12) = *(float4*)(sp + 12);
    float mx = v[0];
#pragma unroll
    for (int i = 1; i < 16; ++i) mx = fmaxf(mx, v[i]);
    mx = fmaxf(mx, __shfl_xor(mx, 1));
    mx = fmaxf(mx, __shfl_xor(mx, 2));
    mx = fmaxf(mx, __shfl_xor(mx, 4));
    float sum = 0.f;
#pragma unroll
    for (int i = 0; i < 16; ++i) { v[i] = expf(v[i] - mx); sum += v[i]; }
    sum += __shfl_xor(sum, 1);
    sum += __shfl_xor(sum, 2);
    sum += __shfl_xor(sum, 4);
    float inv = 1.f / sum;
#pragma unroll
    for (int i = 0; i < 16; ++i) v[i] *= inv;
    *(float4*)(sp) = *(float4*)(v);
    *(float4*)(sp + 4) = *(float4*)(v + 4);
    *(float4*)(sp + 8) = *(float4*)(v + 8);
    *(float4*)(sp + 12) = *(float4*)(v + 12);
  }
  __syncthreads();

  f32x4 oacc[2][2] = {};
#pragma unroll
  for (int ks = 0; ks < 4; ++ks) {
    bf16x8 ph[2], pl[2];
#pragma unroll
    for (int mi = 0; mi < 2; ++mi) {
      float pv[8];
      const float* srow = &S[mi * 16 + lm][ks * 32 + quad * 8];
      *(float4*)(pv) = *(const float4*)srow;
      *(float4*)(pv + 4) = *(const float4*)(srow + 4);
      bf16x8 hh, ll;
#pragma unroll
      for (int i = 0; i < 8; ++i) {
        u16 hb = f2bf(pv[i]);
        hh[i] = (short)hb;
        ll[i] = (short)f2bf(pv[i] - bfu(hb));
      }
      ph[mi] = hh; pl[mi] = ll;
    }
#pragma unroll
    for (int ni = 0; ni < 2; ++ni) {
      size_t vi = (size_t)(g * 512 + h * 128 + w * 32 + ni * 16 + lm) * 128 + ks * 32 + quad * 8;
      bf16x8 vh = *(const bf16x8*)(Vth + vi);
      bf16x8 vl = *(const bf16x8*)(Vtl + vi);
#pragma unroll
      for (int mi = 0; mi < 2; ++mi) {
        oacc[mi][ni] = __builtin_amdgcn_mfma_f32_16x16x32_bf16(ph[mi], vh, oacc[mi][ni], 0, 0, 0);
        oacc[mi][ni] = __builtin_amdgcn_mfma_f32_16x16x32_bf16(pl[mi], vh, oacc[mi][ni], 0, 0, 0);
        oacc[mi][ni] = __builtin_amdgcn_mfma_f32_16x16x32_bf16(ph[mi], vl, oacc[mi][ni], 0, 0, 0);
      }
    }
  }
#pragma unroll
  for (int mi = 0; mi < 2; ++mi)
#pragma unroll
    for (int ni = 0; ni < 2; ++ni)
#pragma unroll
      for (int r = 0; r < 4; ++r) {
        int t = tq * 32 + mi * 16 + quad * 4 + r;
        int d = w * 32 + ni * 16 + lm;
        size_t o = (size_t)(g * 128 + t) * 512 + h * 128 + d;
        float val = oacc[mi][ni][r];
        u16 hb = f2bf(val);
        Oh[o] = hb;
        Ol[o] = f2bf(val - bfu(hb));
      }
}

// emb+pos LN, both encoders (1024 rows): writes fp32 x AND hi/lo planes.
__global__ __launch_bounds__(256) void emb_ln2(
    const void* __restrict__ qe, const void* __restrict__ ae, const void* __restrict__ pos,
    const void* __restrict__ w, const void* __restrict__ b,
    float* __restrict__ x, u16* __restrict__ oh, u16* __restrict__ ol,
    const int* __restrict__ dflag) {
  const int isbf = *dflag;
  const int D = 512;
  int row = blockIdx.x;
  const void* emb = (row < 512) ? qe : ae;
  int lr = row & 511, t = row & 127;
  __shared__ float sbuf[8];
  int i0 = threadIdx.x, i1 = threadIdx.x + 256;
  float v0 = ldin(emb, (size_t)lr * D + i0, isbf) + ldin(pos, (size_t)t * D + i0, isbf);
  float v1 = ldin(emb, (size_t)lr * D + i1, isbf) + ldin(pos, (size_t)t * D + i1, isbf);
  float mean = block_sum(v0 + v1, sbuf) / 512.f;
  float d0 = v0 - mean, d1 = v1 - mean;
  float var = block_sum(d0 * d0 + d1 * d1, sbuf) / 512.f;
  float inv = 1.0f / sqrtf(var + 1e-12f);
  float r0 = ldin(w, i0, isbf) * d0 * inv + ldin(b, i0, isbf);
  float r1 = ldin(w, i1, isbf) * d1 * inv + ldin(b, i1, isbf);
  size_t o0 = (size_t)row * D + i0, o1 = (size_t)row * D + i1;
  x[o0] = r0; x[o1] = r1;
  u16 h0 = f2bf(r0); oh[o0] = h0; ol[o0] = f2bf(r0 - bfu(h0));
  u16 h1 = f2bf(r1); oh[o1] = h1; ol[o1] = f2bf(r1 - bfu(h1));
}

// LN fp32 in -> optional fp32 out (in-place safe) + hi/lo planes.
__global__ __launch_bounds__(256) void ln2(
    const float* __restrict__ in, float* __restrict__ outf,
    u16* __restrict__ oh, u16* __restrict__ ol,
    const void* __restrict__ w, const void* __restrict__ b, size_t wboff,
    const int* __restrict__ dflag) {
  const int isbf = *dflag;
  const int D = 512;
  int row = blockIdx.x;
  __shared__ float sbuf[8];
  int i0 = threadIdx.x, i1 = threadIdx.x + 256;
  float v0 = in[(size_t)row * D + i0];
  float v1 = in[(size_t)row * D + i1];
  float mean = block_sum(v0 + v1, sbuf) / 512.f;
  float d0 = v0 - mean, d1 = v1 - mean;
  float var = block_sum(d0 * d0 + d1 * d1, sbuf) / 512.f;
  float inv = 1.0f / sqrtf(var + 1e-12f);
  float r0 = ldin(w, wboff + i0, isbf) * d0 * inv + ldin(b, wboff + i0, isbf);
  float r1 = ldin(w, wboff + i1, isbf) * d1 * inv + ldin(b, wboff + i1, isbf);
  size_t o0 = (size_t)row * D + i0, o1 = (size_t)row * D + i1;
  if (outf) { outf[o0] = r0; outf[o1] = r1; }
  u16 h0 = f2bf(r0); oh[o0] = h0; ol[o0] = f2bf(r0 - bfu(h0));
  u16 h1 = f2bf(r1); oh[o1] = h1; ol[o1] = f2bf(r1 - bfu(h1));
}

// proj (blocks 0..1023) + gram (blocks 1024..1048), merged.
__global__ __launch_bounds__(64) void projgram(const float* __restrict__ qkb,
                                               const void* __restrict__ ce,
                                               float* __restrict__ ck, float* __restrict__ G,
                                               const int* __restrict__ dflag) {
  const int isbf = *dflag;
  if (blockIdx.x < 1024) {
    int row = blockIdx.x;
#pragma unroll
    for (int c = 0; c < 5; ++c) {
      float acc = 0.f;
      for (int d = threadIdx.x; d < 512; d += 64)
        acc = fmaf(qkb[(size_t)row * 512 + d], ldin(ce, (size_t)c * 512 + d, isbf), acc);
      acc = wave_sum(acc);
      if (threadIdx.x == 0) ck[row * 5 + c] = acc;
    }
  } else {
    int i = blockIdx.x - 1024;
    int c = i / 5, c2 = i % 5;
    float acc = 0.f;
    for (int d = threadIdx.x; d < 512; d += 64)
      acc = fmaf(ldin(ce, (size_t)c * 512 + d, isbf), ldin(ce, (size_t)c2 * 512 + d, isbf), acc);
    acc = wave_sum(acc);
    if (threadIdx.x == 0) G[i] = acc;
  }
}

// Full relation term, t-major:
//   R[b,t,s] = sum_c qa[b,t,s,c]*(kc[b,s,c] + sum_c' G[c,c']*aq[b,s,t,c'])
//            + sum_c aq[b,s,t,c]*qc[b,t,c]
// grid 64 = (t-tile 4, s-tile 4, b 4), 256 threads.
__global__ __launch_bounds__(256) void prep_rel(
    const void* __restrict__ aq, const void* __restrict__ qa,
    const float* __restrict__ ck, const float* __restrict__ G,
    float* __restrict__ R, const int* __restrict__ dflag) {
  const int isbf = *dflag;
  int bx = blockIdx.x;
  int t0 = (bx & 3) * 32;
  int s0 = ((bx >> 2) & 3) * 32;
  int b = bx >> 4;
  int tid = threadIdx.x;
  __shared__ float aqs[32][164];  // [s][t*5+c], pad->4 mod 32 banks
  __shared__ float Gs[25];
  __shared__ float kcs[32][5];
  __shared__ float qcs[32][5];
  for (int i = tid; i < 5120; i += 256) {
    int s = i / 160, r = i % 160;
    aqs[s][r] = ldin(aq, ((size_t)(b * 128 + s0 + s) * 128 + t0) * 5 + r, isbf);
  }
  if (tid < 25) Gs[tid] = G[tid];
  for (int i = tid; i < 160; i += 256)
    kcs[i / 5][i % 5] = ck[(size_t)(512 + b * 128 + s0 + i / 5) * 5 + i % 5];
  for (int i = tid; i < 160; i += 256)
    qcs[i / 5][i % 5] = ck[(size_t)(b * 128 + t0 + i / 5) * 5 + i % 5];
  __syncthreads();
  for (int i = tid; i < 1024; i += 256) {
    int t = i >> 5, s = i & 31;
    size_t qoff = ((size_t)(b * 128 + t0 + t) * 128 + s0 + s) * 5;
    float r = 0.f;
#pragma unroll
    for (int c = 0; c < 5; ++c) {
      float ga = 0.f;
#pragma unroll
      for (int c2 = 0; c2 < 5; ++c2) ga = fmaf(Gs[c * 5 + c2], aqs[s][t * 5 + c2], ga);
      r = fmaf(ldin(qa, qoff + c, isbf), kcs[s][c] + ga, r);
      r = fmaf(aqs[s][t * 5 + c], qcs[t][c], r);
    }
    R[(size_t)(b * 128 + t0 + t) * 128 + s0 + s] = r;
  }
}

// Row softmax + sharpen over S+R; writes transposed PT[b][s][t].
// grid 512 = (b*128+t), 128 threads (s).
__global__ __launch_bounds__(128) void softmax_rel(
    const float* __restrict__ Sbuf, const float* __restrict__ R,
    float* __restrict__ PT) {
  int row = blockIdx.x;          // b*128 + t
  int b = row >> 7, t = row & 127;
  int s = threadIdx.x;
  __shared__ float sbuf[8];
  size_t o = (size_t)row * 128 + s;
  float sc = Sbuf[o] + R[o];
  float mx = block_max(sc, sbuf);
  float e = expf(sc - mx);
  float ssum = block_sum(e, sbuf);
  float p = e / ssum;
  float mx2 = block_max(p, sbuf);
  float e2 = expf(1000.f * (p - mx2));
  float s2 = block_sum(e2, sbuf);
  float pf = fminf(fmaxf(e2 / s2, 0.f), 1.f);
  PT[(size_t)(b * 128 + s) * 128 + t] = pf;
}

// Pbar[b,s] = sum_t PT[b,s,t]; pabarS[bs][c] = sum_t PT[b,s,t]*aq[b,s,t,c].
// grid 512 = (b*128+s), 64 threads (2 t's each). All reads coalesced; no atomics.
__global__ __launch_bounds__(64) void pbar2(
    const float* __restrict__ PT, const void* __restrict__ aq,
    float* __restrict__ Pbar, float* __restrict__ pabarS,
    const int* __restrict__ dflag) {
  const int isbf = *dflag;
  int bs = blockIdx.x;           // b*128 + s
  int lane = threadIdx.x;
  int t0 = lane * 2;
  float2 pt = *(const float2*)(PT + (size_t)bs * 128 + t0);
  size_t ao = ((size_t)bs * 128 + t0) * 5;
  float psum = pt.x + pt.y;
  float pac[5];
#pragma unroll
  for (int c = 0; c < 5; ++c)
    pac[c] = pt.x * ldin(aq, ao + c, isbf) + pt.y * ldin(aq, ao + 5 + c, isbf);
  psum = wave_sum(psum);
#pragma unroll
  for (int c = 0; c < 5; ++c) pac[c] = wave_sum(pac[c]);
  if (lane == 0) {
    Pbar[bs] = psum;
#pragma unroll
    for (int c = 0; c < 5; ++c) pabarS[(size_t)bs * 5 + c] = pac[c];
  }
}

// mean-over-t + classifier from Pbar/pabarS (coalesced k reads only).
__global__ __launch_bounds__(512) void meancls(
    const float* __restrict__ qkb, const float* __restrict__ Pbar,
    const float* __restrict__ pabarS,
    const void* __restrict__ ce, const void* __restrict__ clsw, const void* __restrict__ clsb,
    void* __restrict__ out, const int* __restrict__ dflag) {
  const int isbf = *dflag;
  int b = blockIdx.x;
  int tid = threadIdx.x;
  __shared__ float Ps[128];
  __shared__ float pas[5];
  __shared__ float xm[512];
  __shared__ float sbuf[8];
  if (tid < 5) pas[tid] = 0.f;
  __syncthreads();
  if (tid < 128) {
    Ps[tid] = Pbar[b * 128 + tid];
    const float* ps = pabarS + ((size_t)(b * 128 + tid)) * 5;
    float pac[5] = {ps[0], ps[1], ps[2], ps[3], ps[4]};
#pragma unroll
    for (int c = 0; c < 5; ++c) {
      float v = wave_sum(pac[c]);
      if ((tid & 63) == 0) atomicAdd(&pas[c], v);
    }
  }
  __syncthreads();
  int d = tid;
  const float* k = qkb + (size_t)(512 + b * 128) * 512 + d;
  float acc = 0.f;
  for (int s = 0; s < 128; ++s) acc = fmaf(Ps[s], k[(size_t)s * 512], acc);
#pragma unroll
  for (int c = 0; c < 5; ++c) acc = fmaf(pas[c], ldin(ce, (size_t)c * 512 + d, isbf), acc);
  acc *= (1.f / 128.f);
  xm[d] = acc;
  __syncthreads();
  for (int j = 0; j < 3; ++j) {
    float v = block_sum(xm[d] * ldin(clsw, (size_t)d * 3 + j, isbf), sbuf);
    if (d == 0) {
      float val = v + ldin(clsb, j, isbf);
      if (isbf) ((u16*)out)[b * 3 + j] = f2bf(val);
      else ((float*)out)[b * 3 + j] = val;
    }
    __syncthreads();
  }
}

// ===========================================================================
// fallback round-6 kernels (used only if ws too small for fast path)
// ===========================================================================

__global__ __launch_bounds__(256) void gemm_mfma(
    const float* __restrict__ A, const void* __restrict__ W, size_t woff,
    const void* __restrict__ bias, size_t boff,
    float* __restrict__ C, int M, int N, int K, int act, int addto,
    const int* __restrict__ dflag) {
  const int isbf = *dflag;
  __shared__ __align__(16) u16 Ah[64][40];
  __shared__ __align__(16) u16 Al[64][40];
  __shared__ __align__(16) u16 Wh[64][40];
  __shared__ __align__(16) u16 Wl[64][40];
  int tid = threadIdx.x;
  int row0 = blockIdx.y * 64, col0 = blockIdx.x * 64;
  int wid = tid >> 6, lane = tid & 63;
  int quad = lane >> 4, lm = lane & 15;
  int mrow = (wid & 1) * 32, ncol = (wid >> 1) * 32;
  f32x4 acc[2][2] = {};
  int ar = tid >> 2, akc = (tid & 3) * 8;
  int bk = tid >> 3, bn0 = (tid & 7) * 8;
  for (int k0 = 0; k0 < K; k0 += 32) {
    const float* ap = A + (size_t)(row0 + ar) * K + k0 + akc;
    float av[8];
    *(float4*)(av) = *(const float4*)ap;
    *(float4*)(av + 4) = *(const float4*)(ap + 4);
    unsigned hp[4], lp[4];
#pragma unroll
    for (int j = 0; j < 4; ++j) {
      u16 h0 = f2bf(av[2 * j]);
      u16 h1 = f2bf(av[2 * j + 1]);
      u16 l0 = f2bf(av[2 * j] - bfu(h0));
      u16 l1 = f2bf(av[2 * j + 1] - bfu(h1));
      hp[j] = (unsigned)h0 | ((unsigned)h1 << 16);
      lp[j] = (unsigned)l0 | ((unsigned)l1 << 16);
    }
    *(uint4*)&Ah[ar][akc] = make_uint4(hp[0], hp[1], hp[2], hp[3]);
    *(uint4*)&Al[ar][akc] = make_uint4(lp[0], lp[1], lp[2], lp[3]);
    float wv[8];
    size_t welem = woff + (size_t)(k0 + bk) * N + col0 + bn0;
    if (isbf) {
      const u16* wp = (const u16*)W + welem;
      uint4 raw = *(const uint4*)wp;
      wv[0] = bfu((u16)(raw.x & 0xFFFF)); wv[1] = bfu((u16)(raw.x >> 16));
      wv[2] = bfu((u16)(raw.y & 0xFFFF)); wv[3] = bfu((u16)(raw.y >> 16));
      wv[4] = bfu((u16)(raw.z & 0xFFFF)); wv[5] = bfu((u16)(raw.z >> 16));
      wv[6] = bfu((u16)(raw.w & 0xFFFF)); wv[7] = bfu((u16)(raw.w >> 16));
    } else {
      const float* wp = (const float*)W + welem;
      *(float4*)(wv) = *(const float4*)wp;
      *(float4*)(wv + 4) = *(const float4*)(wp + 4);
    }
#pragma unroll
    for (int i = 0; i < 8; ++i) {
      u16 h = f2bf(wv[i]);
      u16 l = f2bf(wv[i] - bfu(h));
      Wh[bn0 + i][bk] = h;
      Wl[bn0 + i][bk] = l;
    }
    __syncthreads();
#pragma unroll
    for (int mi = 0; mi < 2; ++mi) {
      bf16x8 ah = *(const bf16x8*)&Ah[mrow + mi * 16 + lm][quad * 8];
      bf16x8 al = *(const bf16x8*)&Al[mrow + mi * 16 + lm][quad * 8];
#pragma unroll
      for (int ni = 0; ni < 2; ++ni) {
        bf16x8 wh = *(const bf16x8*)&Wh[ncol + ni * 16 + lm][quad * 8];
        bf16x8 wl = *(const bf16x8*)&Wl[ncol + ni * 16 + lm][quad * 8];
        acc[mi][ni] = __builtin_amdgcn_mfma_f32_16x16x32_bf16(ah, wh, acc[mi][ni], 0, 0, 0);
        acc[mi][ni] = __builtin_amdgcn_mfma_f32_16x16x32_bf16(al, wh, acc[mi][ni], 0, 0, 0);
        acc[mi][ni] = __builtin_amdgcn_mfma_f32_16x16x32_bf16(ah, wl, acc[mi][ni], 0, 0, 0);
      }
    }
    __syncthreads();
  }
#pragma unroll
  for (int mi = 0; mi < 2; ++mi) {
#pragma unroll
    for (int ni = 0; ni < 2; ++ni) {
      int colg = col0 + ncol + ni * 16 + lm;
      float bv = ldin(bias, boff + colg, isbf);
#pragma unroll
      for (int r = 0; r < 4; ++r) {
        int rowg = row0 + mrow + mi * 16 + quad * 4 + r;
        float v = acc[mi][ni][r] + bv;
        if (act) v = v * 0.5f * (1.f + erff(v * 0.70710678118654752f));
        size_t o = (size_t)rowg * N + colg;
        if (addto) C[o] += v; else C[o] = v;
      }
    }
  }
}

__global__ __launch_bounds__(256) void emb_ln_kernel(const void* __restrict__ emb,
                                                     const void* __restrict__ pos,
                                                     const void* __restrict__ w,
                                                     const void* __restrict__ b,
                                                     float* __restrict__ out, int T, int D,
                                                     const int* __restrict__ dflag) {
  const int isbf = *dflag;
  int row = blockIdx.x;
  int t = row % T;
  __shared__ float sbuf[8];
  int i0 = threadIdx.x, i1 = threadIdx.x + 256;
  float v0 = ldin(emb, (size_t)row * D + i0, isbf) + ldin(pos, (size_t)t * D + i0, isbf);
  float v1 = ldin(emb, (size_t)row * D + i1, isbf) + ldin(pos, (size_t)t * D + i1, isbf);
  float mean = block_sum(v0 + v1, sbuf) / (float)D;
  float d0 = v0 - mean, d1 = v1 - mean;
  float var = block_sum(d0 * d0 + d1 * d1, sbuf) / (float)D;
  float inv = 1.0f / sqrtf(var + 1e-12f);
  out[(size_t)row * D + i0] = ldin(w, i0, isbf) * d0 * inv + ldin(b, i0, isbf);
  out[(size_t)row * D + i1] = ldin(w, i1, isbf) * d1 * inv + ldin(b, i1, isbf);
}

__global__ __launch_bounds__(256) void ln_kernel(const float* __restrict__ in, float* __restrict__ out,
                                                 const void* __restrict__ w, const void* __restrict__ b,
                                                 size_t wboff, int D, const int* __restrict__ dflag) {
  const int isbf = *dflag;
  int row = blockIdx.x;
  __shared__ float sbuf[8];
  int i0 = threadIdx.x, i1 = threadIdx.x + 256;
  float v0 = in[(size_t)row * D + i0];
  float v1 = in[(size_t)row * D + i1];
  float mean = block_sum(v0 + v1, sbuf) / (float)D;
  float d0 = v0 - mean, d1 = v1 - mean;
  float var = block_sum(d0 * d0 + d1 * d1, sbuf) / (float)D;
  float inv = 1.0f / sqrtf(var + 1e-12f);
  out[(size_t)row * D + i0] = ldin(w, wboff + i0, isbf) * d0 * inv + ldin(b, wboff + i0, isbf);
  out[(size_t)row * D + i1] = ldin(w, wboff + i1, isbf) * d1 * inv + ldin(b, wboff + i1, isbf);
}

__global__ __launch_bounds__(128) void attn_kernel(const float* __restrict__ q, const float* __restrict__ k,
                                                   const float* __restrict__ v, float* __restrict__ o,
                                                   int B, int H, int T, int dk) {
  int t = blockIdx.x % T;
  int h = (blockIdx.x / T) % H;
  int b = blockIdx.x / (T * H);
  int D = H * dk;
  int tid = threadIdx.x;
  __shared__ float qs[128];
  __shared__ float ps[128];
  __shared__ float sbuf[8];
  qs[tid] = q[(size_t)(b * T + t) * D + h * dk + tid];
  __syncthreads();
  const float* krow = k + (size_t)(b * T + tid) * D + h * dk;
  float sc = 0.f;
#pragma unroll 8
  for (int d = 0; d < 128; ++d) sc = fmaf(qs[d], krow[d], sc);
  sc *= 0.08838834764831845f;
  float mx = block_max(sc, sbuf);
  float e = expf(sc - mx);
  float s = block_sum(e, sbuf);
  ps[tid] = e / s;
  __syncthreads();
  float acc = 0.f;
  for (int s2 = 0; s2 < 128; ++s2)
    acc = fmaf(ps[s2], v[(size_t)(b * T + s2) * D + h * dk + tid], acc);
  o[(size_t)(b * T + t) * D + h * dk + tid] = acc;
}

__global__ __launch_bounds__(64) void proj_ce_kernel(const float* __restrict__ q,
                                                     const void* __restrict__ ce,
                                                     float* __restrict__ out, int D, int NC,
                                                     const int* __restrict__ dflag) {
  const int isbf = *dflag;
  int row = blockIdx.x;
  for (int c = 0; c < NC; ++c) {
    float acc = 0.f;
    for (int d = threadIdx.x; d < D; d += 64)
      acc = fmaf(q[(size_t)row * D + d], ldin(ce, (size_t)c * D + d, isbf), acc);
    acc = wave_sum(acc);
    if (threadIdx.x == 0) out[row * NC + c] = acc;
  }
}

__global__ __launch_bounds__(64) void gram_kernel(const void* __restrict__ ce,
                                                  float* __restrict__ G, int D, int NC,
                                                  const int* __restrict__ dflag) {
  const int isbf = *dflag;
  int c = blockIdx.x / NC, c2 = blockIdx.x % NC;
  float acc = 0.f;
  for (int d = threadIdx.x; d < D; d += 64)
    acc = fmaf(ldin(ce, (size_t)c * D + d, isbf), ldin(ce, (size_t)c2 * D + d, isbf), acc);
  acc = wave_sum(acc);
  if (threadIdx.x == 0) G[blockIdx.x] = acc;
}

__global__ __launch_bounds__(128) void sim_scores_kernel(
    const float* __restrict__ q, const float* __restrict__ k, const void* __restrict__ qa,
    const void* __restrict__ aq, const float* __restrict__ qc, const float* __restrict__ kc,
    const float* __restrict__ G, float* __restrict__ p_out, float* __restrict__ pa_out,
    int B, int T1, int T2, int D, int NC, const int* __restrict__ dflag) {
  const int isbf = *dflag;
  int t = blockIdx.x % T1;
  int b = blockIdx.x / T1;
  int s = threadIdx.x;
  __shared__ float qs[512];
  __shared__ float Gs[25];
  __shared__ float qcs[5];
  __shared__ float sbuf[8];
  for (int i = threadIdx.x; i < D; i += 128) qs[i] = q[(size_t)(b * T1 + t) * D + i];
  if (threadIdx.x < NC * NC) Gs[threadIdx.x] = G[threadIdx.x];
  if (threadIdx.x < NC) qcs[threadIdx.x] = qc[(b * T1 + t) * NC + threadIdx.x];
  __syncthreads();
  const float* krow = k + (size_t)(b * T2 + s) * D;
  float sc = 0.f;
#pragma unroll 8
  for (int d = 0; d < 512; ++d) sc = fmaf(qs[d], krow[d], sc);
  float qav[5], aqv[5];
#pragma unroll
  for (int c = 0; c < 5; ++c) {
    qav[c] = ldin(qa, (size_t)((b * T1 + t) * T2 + s) * NC + c, isbf);
    aqv[c] = ldin(aq, (size_t)((b * T2 + s) * T1 + t) * NC + c, isbf);
  }
#pragma unroll
  for (int c = 0; c < 5; ++c) {
    sc = fmaf(aqv[c], qcs[c], sc);
    sc = fmaf(qav[c], kc[(b * T2 + s) * NC + c], sc);
#pragma unroll
    for (int c2 = 0; c2 < 5; ++c2) sc = fmaf(qav[c] * Gs[c * 5 + c2], aqv[c2], sc);
  }
  float mx = block_max(sc, sbuf);
  float e = expf(sc - mx);
  float ssum = block_sum(e, sbuf);
  float p = e / ssum;
  float mx2 = block_max(p, sbuf);
  float e2 = expf(1000.f * (p - mx2));
  float s2 = block_sum(e2, sbuf);
  float pf = fminf(fmaxf(e2 / s2, 0.f), 1.f);
  p_out[(size_t)(b * T1 + t) * T2 + s] = pf;
#pragma unroll
  for (int c = 0; c < 5; ++c) {
    float pc = block_sum(pf * aqv[c], sbuf);
    if (threadIdx.x == 0) pa_out[(b * T1 + t) * NC + c] = pc;
  }
}

__global__ __launch_bounds__(512) void sim_x_kernel(const float* __restrict__ p, const float* __restrict__ k,
                                                    const float* __restrict__ pa,
                                                    const void* __restrict__ ce,
                                                    float* __restrict__ x, int B, int T1, int T2, int D, int NC,
                                                    const int* __restrict__ dflag) {
  const int isbf = *dflag;
  int t = blockIdx.x % T1;
  int b = blockIdx.x / T1;
  int d = threadIdx.x;
  __shared__ float ps[128];
  __shared__ float pav[5];
  if (threadIdx.x < T2) ps[threadIdx.x] = p[(size_t)(b * T1 + t) * T2 + threadIdx.x];
  if (threadIdx.x < NC) pav[threadIdx.x] = pa[(b * T1 + t) * NC + threadIdx.x];
  __syncthreads();
  float acc = 0.f;
  for (int s = 0; s < 128; ++s) acc = fmaf(ps[s], k[(size_t)(b * T2 + s) * D + d], acc);
#pragma unroll
  for (int c = 0; c < 5; ++c) acc = fmaf(pav[c], ldin(ce, (size_t)c * D + d, isbf), acc);
  x[(size_t)(b * T1 + t) * D + d] = acc;
}

__global__ __launch_bounds__(512) void mean_kernel(const float* __restrict__ x, float* __restrict__ xm,
                                                   int T, int D) {
  int b = blockIdx.x;
  int d = threadIdx.x;
  float acc = 0.f;
  for (int t = 0; t < T; ++t) acc += x[(size_t)(b * T + t) * D + d];
  xm[(size_t)b * D + d] = acc / (float)T;
}

__global__ __launch_bounds__(64) void cls_kernel(const float* __restrict__ xm,
                                                 const void* __restrict__ w,
                                                 const void* __restrict__ bias,
                                                 void* __restrict__ out, int D, int NO,
                                                 const int* __restrict__ dflag) {
  const int isbf = *dflag;
  int j = blockIdx.x % NO;
  int b = blockIdx.x / NO;
  float acc = 0.f;
  for (int d = threadIdx.x; d < D; d += 64)
    acc = fmaf(xm[(size_t)b * D + d], ldin(w, (size_t)d * NO + j, isbf), acc);
  acc = wave_sum(acc);
  if (threadIdx.x == 0) {
    float val = acc + ldin(bias, j, isbf);
    if (isbf) ((__hip_bfloat16*)out)[b * NO + j] = __float2bfloat16(val);
    else ((float*)out)[b * NO + j] = val;
  }
}

// ===========================================================================
extern "C" void kernel_launch(void* const* d_in, const int* in_sizes, int n_in,
                              void* d_out, int out_size, void* d_ws, size_t ws_size,
                              hipStream_t stream) {
  const int B = 4, T = 128, D = 512, H = 4, NL = 4, DFF = 2048, NC = 5;
  const void *q_emb = d_in[0], *a_emb = d_in[1], *qa = d_in[2], *aqr = d_in[3],
             *ce = d_in[4], *pos = d_in[5], *pe_w = d_in[6], *pe_b = d_in[7],
             *Wq = d_in[8], *bq = d_in[9], *Wk = d_in[10], *bk = d_in[11],
             *Wv = d_in[12], *bv = d_in[13], *Wo = d_in[14], *bo = d_in[15],
             *ff1w = d_in[16], *ff1b = d_in[17], *ff2w = d_in[18], *ff2b = d_in[19],
             *lnin_w = d_in[20], *lnin_b = d_in[21], *lnout_w = d_in[22], *lnout_b = d_in[23],
             *simWq = d_in[24], *simbq = d_in[25], *simWk = d_in[26], *simbk = d_in[27],
             *clsw = d_in[28], *clsb = d_in[29];

  const size_t REQ = 83000000ull;  // poison-fill showed ws ~268 MB; fallback if smaller
  if (ws_size >= REQ) {
    // -------- FAST PATH --------
    char* base = (char*)d_ws;
    float* x = (float*)(base + 0);
    u16* xch = (u16*)(base + 2097152);
    u16* xcl = (u16*)(base + 3145728);
    u16* qkvh = (u16*)(base + 4194304);
    u16* qkvl = (u16*)(base + 7340032);
    u16* ffch = (u16*)(base + 10485760);
    u16* ffcl = (u16*)(base + 14680064);
    u16* Vth = (u16*)(base + 18874368);
    u16* Vtl = (u16*)(base + 19922944);
    float* qkb = (float*)(base + 20971520);        // [1024][512] fp32 sim q|k
    u16* qsh = (u16*)(base + 23068672);            // sim q|k hi plane [1024][512]
    u16* qsl = (u16*)(base + 24117248);            // lo
    float* ck = (float*)(base + 25165824);         // [1024][5]
    float* Gbuf = (float*)(base + 25186304);       // 25
    float* Pbar = (float*)(base + 25190400);       // [4][128]
    int* dflag = (int*)(base + 25196544);
    u16* wh = (u16*)(base + 26214400);             // 13,107,200 elems
    u16* wl = (u16*)(base + 52428800);
    float* Sbuf = (float*)(base + 79691776);       // [4][128][128] scores (256 KB)
    float* R = (float*)(base + 79953920);          // [4][128][128] relation (256 KB)
    float* PT = (float*)(base + 80216064);         // [4][128][128] sharpened P^T (256 KB)
    float* pabarS = (float*)(base + 80478208);     // [512][5] partials (10 KB)
    // wAll layout per layer l (base l*3145728): QKVO T [2048][512] | FF1 T | FF2 T [512][2048]
    // sim at +12582912: [1024][512]

    flag_kernel<<<1, 64, 0, stream>>>(pe_w, dflag);
    convT_all<<<dim3(16, 16, 50), 256, 0, stream>>>(Wq, Wk, Wv, Wo, ff1w, ff2w,
                                                    simWq, simWk, wh, wl, dflag);
    emb_ln2<<<1024, 256, 0, stream>>>(q_emb, a_emb, pos, pe_w, pe_b, x, xch, xcl, dflag);

    for (int l = 0; l < NL; ++l) {
      size_t wbase = (size_t)l * 3145728, bD = (size_t)l * D;
      gemm_hl<<<dim3(24, 16, 1), 256, 0, stream>>>(xch, xcl, 512, wh + wbase, wl + wbase, 512,
                                                   bq, bk, bv, bD, bD, bD, 9,
                                                   nullptr, qkvh, qkvl, Vth, Vtl, 1536,
                                                   512, 0, 3, 9999, 0, dflag);
      attn_mfma<<<128, 256, 0, stream>>>(qkvh, qkvl, Vth, Vtl, xch, xcl);
      gemm_hl<<<dim3(8, 16, 2), 256, 0, stream>>>(xch, xcl, 512, wh + wbase + 786432,
                                                  wl + wbase + 786432, 512,
                                                  bo, bo, bo, bD, bD, bD, 9,
                                                  x, nullptr, nullptr, nullptr, nullptr, 512,
                                                  512, 0, 1, 9999, 0, dflag);
      ln2<<<1024, 256, 0, stream>>>(x, nullptr, xch, xcl, lnin_w, lnin_b, bD, dflag);
      gemm_hl<<<dim3(32, 16, 1), 256, 0, stream>>>(xch, xcl, 512, wh + wbase + 1048576,
                                                   wl + wbase + 1048576, 512,
                                                   ff1b, ff1b, ff1b,
                                                   (size_t)l * DFF, (size_t)l * DFF, (size_t)l * DFF, 11,
                                                   nullptr, ffch, ffcl, nullptr, nullptr, 2048,
                                                   512, 1, 2, 9999, 0, dflag);
      gemm_hl<<<dim3(8, 16, 2), 256, 0, stream>>>(ffch, ffcl, 2048, wh + wbase + 2097152,
                                                  wl + wbase + 2097152, 2048,
                                                  ff2b, ff2b, ff2b, bD, bD, bD, 9,
                                                  x, nullptr, nullptr, nullptr, nullptr, 512,
                                                  2048, 0, 1, 9999, 0, dflag);
      ln2<<<1024, 256, 0, stream>>>(x, x, xch, xcl, lnout_w, lnout_b, bD, dflag);
    }

    // Sim head
    gemm_hl<<<dim3(8, 16, 1), 256, 0, stream>>>(xch, xcl, 512, wh + 12582912, wl + 12582912, 512,
                                                simbq, simbk, simbk, 0, 0, 0, 9,
                                                qkb, qsh, qsl, nullptr, nullptr, 512,
                                                512, 0, 4, 8, 512, dflag);
    projgram<<<1049, 64, 0, stream>>>(qkb, ce, ck, Gbuf, dflag);
    prep_rel<<<64, 256, 0, stream>>>(aqr, qa, ck, Gbuf, R, dflag);
    // S = q @ k^T (batched over b, single-z, plain store -> no init needed)
    gemm_hl<<<dim3(2, 8, 1), 256, 0, stream>>>(qsh, qsl, 512, qsh, qsl, 512,
                                               nullptr, nullptr, nullptr, 0, 0, 0, 9,
                                               Sbuf, nullptr, nullptr, nullptr, nullptr, 128,
                                               512, 0, 6, 9999, 512, dflag);
    softmax_rel<<<512, 128, 0, stream>>>(Sbuf, R, PT);
    pbar2<<<512, 64, 0, stream>>>(PT, aqr, Pbar, pabarS, dflag);
    meancls<<<4, 512, 0, stream>>>(qkb, Pbar, pabarS, ce, clsw, clsb, d_out, dflag);
    return;
  }

  // -------- FALLBACK: round-6 passing path --------
  float* ws = (float*)d_ws;
  const size_t S = (size_t)512 * 512;
  float* qe = ws;
  float* ae = ws + S;
  float* hb = ws + 2 * S;
  float* rb = ws + 3 * S;
  float* qb = rb;
  float* kb = rb + S;
  float* vb = rb + 2 * S;
  float* ob = rb + 3 * S;
  float* ffb = rb;
  float* pbuf = rb + 2 * S;
  float* pabuf = pbuf + 65536;
  float* qcbuf = pabuf + 2560;
  float* kcbuf = qcbuf + 2560;
  float* Gbuf = kcbuf + 2560;
  float* xmean = Gbuf + 32;
  float* xsim = rb + 3 * S;
  int* dflag = (int*)(ws + 7 * S);

  const int M = B * T;
  dim3 gD(8, 8), gF1(32, 8), gF2(8, 8);

  flag_kernel<<<1, 64, 0, stream>>>(pe_w, dflag);
  for (int e = 0; e < 2; ++e) {
    float* x = (e == 0) ? qe : ae;
    const void* emb = (e == 0) ? q_emb : a_emb;
    emb_ln_kernel<<<M, 256, 0, stream>>>(emb, pos, pe_w, pe_b, x, T, D, dflag);
    for (int l = 0; l < NL; ++l) {
      size_t wDD = (size_t)l * D * D, bD = (size_t)l * D;
      gemm_mfma<<<gD, 256, 0, stream>>>(x, Wq, wDD, bq, bD, qb, M, D, D, 0, 0, dflag);
      gemm_mfma<<<gD, 256, 0, stream>>>(x, Wk, wDD, bk, bD, kb, M, D, D, 0, 0, dflag);
      gemm_mfma<<<gD, 256, 0, stream>>>(x, Wv, wDD, bv, bD, vb, M, D, D, 0, 0, dflag);
      attn_kernel<<<B * H * T, 128, 0, stream>>>(qb, kb, vb, ob, B, H, T, D / H);
      gemm_mfma<<<gD, 256, 0, stream>>>(ob, Wo, wDD, bo, bD, x, M, D, D, 0, 1, dflag);
      ln_kernel<<<M, 256, 0, stream>>>(x, hb, lnin_w, lnin_b, bD, D, dflag);
      gemm_mfma<<<gF1, 256, 0, stream>>>(hb, ff1w, (size_t)l * D * DFF, ff1b, (size_t)l * DFF,
                                         ffb, M, DFF, D, 1, 0, dflag);
      gemm_mfma<<<gF2, 256, 0, stream>>>(ffb, ff2w, (size_t)l * DFF * D, ff2b, bD,
                                         x, M, D, DFF, 0, 1, dflag);
      ln_kernel<<<M, 256, 0, stream>>>(x, x, lnout_w, lnout_b, bD, D, dflag);
    }
  }
  gemm_mfma<<<gD, 256, 0, stream>>>(qe, simWq, 0, simbq, 0, qb, M, D, D, 0, 0, dflag);
  gemm_mfma<<<gD, 256, 0, stream>>>(ae, simWk, 0, simbk, 0, kb, M, D, D, 0, 0, dflag);
  proj_ce_kernel<<<M, 64, 0, stream>>>(qb, ce, qcbuf, D, NC, dflag);
  proj_ce_kernel<<<M, 64, 0, stream>>>(kb, ce, kcbuf, D, NC, dflag);
  gram_kernel<<<NC * NC, 64, 0, stream>>>(ce, Gbuf, D, NC, dflag);
  sim_scores_kernel<<<B * T, 128, 0, stream>>>(qb, kb, qa, aqr, qcbuf, kcbuf, Gbuf, pbuf, pabuf,
                                               B, T, T, D, NC, dflag);
  sim_x_kernel<<<B * T, 512, 0, stream>>>(pbuf, kb, pabuf, ce, xsim, B, T, T, D, NC, dflag);
  mean_kernel<<<B, 512, 0, stream>>>(xsim, xmean, T, D);
  cls_kernel<<<B * 3, 64, 0, stream>>>(xmean, clsw, clsb, d_out, D, 3, dflag);
}

// Round 14
// 581.004 us; speedup vs baseline: 1.0807x; 1.0215x over previous
//
#include <hip/hip_runtime.h>
#include <hip/hip_bf16.h>
#include <math.h>

typedef unsigned short u16;
typedef __attribute__((ext_vector_type(8))) short bf16x8;   // 8 bf16 (4 VGPRs)
typedef __attribute__((ext_vector_type(4))) float f32x4;

// Inputs may be bf16 or fp32. Each fast-path kernel derives the dtype flag
// directly from pe_w (all-ones: first u16 is 0x3F80 iff bf16, 0x0000 iff fp32).
__device__ __forceinline__ float ldin(const void* p, size_t i, int isbf) {
  if (isbf) return __bfloat162float(((const __hip_bfloat16*)p)[i]);
  return ((const float*)p)[i];
}
__device__ __forceinline__ float bfu(u16 u) { return __builtin_bit_cast(float, (unsigned)u << 16); }
__device__ __forceinline__ u16 f2bf(float x) {  // round-to-nearest-even
  unsigned u = __builtin_bit_cast(unsigned, x);
  unsigned r = u + 0x7FFFu + ((u >> 16) & 1u);
  return (u16)(r >> 16);
}
__device__ __forceinline__ int getbf(const void* pe_w) {
  return ((const u16*)pe_w)[0] != 0;
}

__device__ __forceinline__ float wave_sum(float v) {
#pragma unroll
  for (int o = 32; o > 0; o >>= 1) v += __shfl_down(v, o);
  return v;
}

__device__ __forceinline__ float block_sum(float v, float* sbuf) {
  int lane = threadIdx.x & 63;
  int wid = threadIdx.x >> 6;
#pragma unroll
  for (int o = 32; o > 0; o >>= 1) v += __shfl_down(v, o);
  __syncthreads();
  if (lane == 0) sbuf[wid] = v;
  __syncthreads();
  int nw = blockDim.x >> 6;
  if (wid == 0) {
    float r = (lane < nw) ? sbuf[lane] : 0.f;
#pragma unroll
    for (int o = 4; o > 0; o >>= 1) r += __shfl_down(r, o);
    if (lane == 0) sbuf[0] = r;
  }
  __syncthreads();
  return sbuf[0];
}

__device__ __forceinline__ float block_max(float v, float* sbuf) {
  int lane = threadIdx.x & 63;
  int wid = threadIdx.x >> 6;
#pragma unroll
  for (int o = 32; o > 0; o >>= 1) v = fmaxf(v, __shfl_down(v, o));
  __syncthreads();
  if (lane == 0) sbuf[wid] = v;
  __syncthreads();
  int nw = blockDim.x >> 6;
  if (wid == 0) {
    float r = (lane < nw) ? sbuf[lane] : -INFINITY;
#pragma unroll
    for (int o = 4; o > 0; o >>= 1) r = fmaxf(r, __shfl_down(r, o));
    if (lane == 0) sbuf[0] = r;
  }
  __syncthreads();
  return sbuf[0];
}

__global__ void flag_kernel(const void* pe_w, int* flag) {
  if (threadIdx.x == 0 && blockIdx.x == 0)
    *flag = (((const unsigned short*)pe_w)[0] != 0) ? 1 : 0;
}

// ===========================================================================
// FAST PATH kernels
// ===========================================================================

// ALL weight convert+transpose + emb-LN in one launch. grid (16,16,54):
//   [0,16)  QKVO: t=z&3, l=z>>2            src [512][512]  -> l*3145728 + t*262144
//   [16,32) FF1:  l=(z-16)>>2, xg=(z-16)&3 src [512][2048] -> l*3145728 + 1048576
//   [32,48) FF2:  l=(z-32)>>2, yg=(z-32)&3 src [2048][512] -> l*3145728 + 2097152
//   48,49   simWq/simWk [512][512]         -> 12582912 + (z-48)*262144
//   [50,54) emb+pos LN rows (z-50)*256 + y*16 + x  -> xf + planes
__global__ __launch_bounds__(256) void convT_all(
    const void* __restrict__ Wq, const void* __restrict__ Wk,
    const void* __restrict__ Wv, const void* __restrict__ Wo,
    const void* __restrict__ ff1w, const void* __restrict__ ff2w,
    const void* __restrict__ simWq, const void* __restrict__ simWk,
    u16* __restrict__ Dh, u16* __restrict__ Dl,
    const void* __restrict__ q_emb, const void* __restrict__ a_emb,
    const void* __restrict__ pos, const void* __restrict__ pe_w,
    const void* __restrict__ pe_b,
    float* __restrict__ xf, u16* __restrict__ xh, u16* __restrict__ xl) {
  const int isbf = getbf(pe_w);
  int z = blockIdx.z, x = blockIdx.x, y = blockIdx.y;
  if (z >= 50) {
    // ---- emb+pos LN body (row per block, 256 threads) ----
    const int D = 512;
    int row = (z - 50) * 256 + y * 16 + x;
    const void* emb = (row < 512) ? q_emb : a_emb;
    int lr = row & 511, t = row & 127;
    __shared__ float sbuf[8];
    int i0 = threadIdx.x, i1 = threadIdx.x + 256;
    float v0 = ldin(emb, (size_t)lr * D + i0, isbf) + ldin(pos, (size_t)t * D + i0, isbf);
    float v1 = ldin(emb, (size_t)lr * D + i1, isbf) + ldin(pos, (size_t)t * D + i1, isbf);
    float mean = block_sum(v0 + v1, sbuf) / 512.f;
    float d0 = v0 - mean, d1 = v1 - mean;
    float var = block_sum(d0 * d0 + d1 * d1, sbuf) / 512.f;
    float inv = 1.0f / sqrtf(var + 1e-12f);
    float r0 = ldin(pe_w, i0, isbf) * d0 * inv + ldin(pe_b, i0, isbf);
    float r1 = ldin(pe_w, i1, isbf) * d1 * inv + ldin(pe_b, i1, isbf);
    size_t o0 = (size_t)row * D + i0, o1 = (size_t)row * D + i1;
    xf[o0] = r0; xf[o1] = r1;
    u16 h0 = f2bf(r0); xh[o0] = h0; xl[o0] = f2bf(r0 - bfu(h0));
    u16 h1 = f2bf(r1); xh[o1] = h1; xl[o1] = f2bf(r1 - bfu(h1));
    return;
  }
  const void* S;
  size_t soff, doff;
  int K, N, n0, k0;
  if (z < 16) {
    int t = z & 3, l = z >> 2;
    S = (t == 0) ? Wq : ((t == 1) ? Wk : ((t == 2) ? Wv : Wo));
    soff = (size_t)l * 262144; K = 512; N = 512;
    doff = (size_t)l * 3145728 + (size_t)t * 262144;
    n0 = x * 32; k0 = y * 32;
  } else if (z < 32) {
    int idx = z - 16, l = idx >> 2, xg = idx & 3;
    S = ff1w; soff = (size_t)l * 1048576; K = 512; N = 2048;
    doff = (size_t)l * 3145728 + 1048576;
    n0 = (xg * 16 + x) * 32; k0 = y * 32;
  } else if (z < 48) {
    int idx = z - 32, l = idx >> 2, yg = idx & 3;
    S = ff2w; soff = (size_t)l * 1048576; K = 2048; N = 512;
    doff = (size_t)l * 3145728 + 2097152;
    n0 = x * 32; k0 = (yg * 16 + y) * 32;
  } else {
    S = (z == 48) ? simWq : simWk;
    soff = 0; K = 512; N = 512;
    doff = 12582912 + (size_t)(z - 48) * 262144;
    n0 = x * 32; k0 = y * 32;
  }
  __shared__ float tt[32][33];
  int tx = threadIdx.x & 31, ty = threadIdx.x >> 5;
#pragma unroll
  for (int j = 0; j < 4; ++j) {
    int r = ty + j * 8;
    tt[r][tx] = ldin(S, soff + (size_t)(k0 + r) * N + n0 + tx, isbf);
  }
  __syncthreads();
#pragma unroll
  for (int j = 0; j < 4; ++j) {
    int r = ty + j * 8;
    float v = tt[tx][r];
    u16 h = f2bf(v);
    u16 lo = f2bf(v - bfu(h));
    size_t o = doff + (size_t)(n0 + r) * K + k0 + tx;
    Dh[o] = h;
    Dl[o] = lo;
  }
}

// MFMA GEMM on pre-split hi/lo planes.
// mode: 0 = store fp32 C, 1 = atomicAdd (split-K via gridDim.z; bias only z==0),
//       2 = store hi/lo planes, 3 = QKV (V transposed), 4 = fp32 C AND planes.
__global__ __launch_bounds__(256) void gemm_hl(
    const u16* __restrict__ Ahp, const u16* __restrict__ Alp, int lda,
    const u16* __restrict__ Whp, const u16* __restrict__ Wlp, int ldw,
    const void* __restrict__ b0, const void* __restrict__ b1, const void* __restrict__ b2,
    size_t bo0, size_t bo1, size_t bo2, int bshift,
    float* __restrict__ C, u16* __restrict__ Chp, u16* __restrict__ Clp,
    u16* __restrict__ Vh, u16* __restrict__ Vl, int ldc,
    int K, int act, int mode, int ysplit, size_t wrowoff1,
    const void* __restrict__ pe_w) {
  const int isbf = getbf(pe_w);
  __shared__ __align__(16) u16 sAh[64][72];
  __shared__ __align__(16) u16 sAl[64][72];
  __shared__ __align__(16) u16 sBh[64][72];
  __shared__ __align__(16) u16 sBl[64][72];

  int tid = threadIdx.x;
  int by = blockIdx.y;
  int row0 = by * 64, col0 = blockIdx.x * 64;
  int rsplit = (by >= ysplit);
  size_t wrow0 = (size_t)col0 + (rsplit ? wrowoff1 : 0);
  int Ksub = K / (int)gridDim.z;
  int kstart = (int)blockIdx.z * Ksub;
  int addbias = (blockIdx.z == 0);

  int wid = tid >> 6, lane = tid & 63, quad = lane >> 4, lm = lane & 15;
  int mrow = (wid & 1) * 32, ncol = (wid >> 1) * 32;

  f32x4 acc[2][2] = {};

  int sr = tid >> 2, sc = (tid & 3) * 16;

  for (int k0 = kstart; k0 < kstart + Ksub; k0 += 64) {
    const u16* p;
    p = Ahp + (size_t)(row0 + sr) * lda + k0 + sc;
    uint4 a0 = *(const uint4*)p, a1 = *(const uint4*)(p + 8);
    p = Alp + (size_t)(row0 + sr) * lda + k0 + sc;
    uint4 a2 = *(const uint4*)p, a3 = *(const uint4*)(p + 8);
    p = Whp + (wrow0 + sr) * (size_t)ldw + k0 + sc;
    uint4 w0 = *(const uint4*)p, w1 = *(const uint4*)(p + 8);
    p = Wlp + (wrow0 + sr) * (size_t)ldw + k0 + sc;
    uint4 w2 = *(const uint4*)p, w3 = *(const uint4*)(p + 8);
    __syncthreads();
    *(uint4*)&sAh[sr][sc] = a0; *(uint4*)&sAh[sr][sc + 8] = a1;
    *(uint4*)&sAl[sr][sc] = a2; *(uint4*)&sAl[sr][sc + 8] = a3;
    *(uint4*)&sBh[sr][sc] = w0; *(uint4*)&sBh[sr][sc + 8] = w1;
    *(uint4*)&sBl[sr][sc] = w2; *(uint4*)&sBl[sr][sc + 8] = w3;
    __syncthreads();
#pragma unroll
    for (int ks = 0; ks < 2; ++ks) {
      bf16x8 ah[2], al[2], wh[2], wl[2];
#pragma unroll
      for (int mi = 0; mi < 2; ++mi) {
        ah[mi] = *(const bf16x8*)&sAh[mrow + mi * 16 + lm][ks * 32 + quad * 8];
        al[mi] = *(const bf16x8*)&sAl[mrow + mi * 16 + lm][ks * 32 + quad * 8];
      }
#pragma unroll
      for (int ni = 0; ni < 2; ++ni) {
        wh[ni] = *(const bf16x8*)&sBh[ncol + ni * 16 + lm][ks * 32 + quad * 8];
        wl[ni] = *(const bf16x8*)&sBl[ncol + ni * 16 + lm][ks * 32 + quad * 8];
      }
#pragma unroll
      for (int mi = 0; mi < 2; ++mi)
#pragma unroll
        for (int ni = 0; ni < 2; ++ni) {
          acc[mi][ni] = __builtin_amdgcn_mfma_f32_16x16x32_bf16(ah[mi], wh[ni], acc[mi][ni], 0, 0, 0);
          acc[mi][ni] = __builtin_amdgcn_mfma_f32_16x16x32_bf16(al[mi], wh[ni], acc[mi][ni], 0, 0, 0);
          acc[mi][ni] = __builtin_amdgcn_mfma_f32_16x16x32_bf16(ah[mi], wl[ni], acc[mi][ni], 0, 0, 0);
        }
    }
  }
#pragma unroll
  for (int mi = 0; mi < 2; ++mi) {
#pragma unroll
    for (int ni = 0; ni < 2; ++ni) {
      int colg = col0 + ncol + ni * 16 + lm;
      float bv = 0.f;
      if (addbias) {
        const void* bp; size_t bo;
        if (rsplit) { bp = b1; bo = bo1 + colg; }
        else {
          int seg = colg >> bshift;
          bp = (seg == 0) ? b0 : ((seg == 1) ? b1 : b2);
          bo = (seg == 0) ? bo0 : ((seg == 1) ? bo1 : bo2);
          bo += (size_t)colg - ((size_t)seg << bshift);
        }
        bv = ldin(bp, bo, isbf);
      }
#pragma unroll
      for (int r = 0; r < 4; ++r) {
        int rowg = row0 + mrow + mi * 16 + quad * 4 + r;
        float v = acc[mi][ni][r] + bv;
        if (act) v = v * 0.5f * (1.f + erff(v * 0.70710678118654752f));
        if (mode == 3 && colg >= 1024) {
          int gg = rowg >> 7;
          size_t o = ((size_t)(gg * 512) + (colg - 1024)) * 128 + (rowg & 127);
          u16 hh = f2bf(v); Vh[o] = hh; Vl[o] = f2bf(v - bfu(hh));
        } else {
          size_t o = (size_t)rowg * ldc + colg;
          if (mode == 0) C[o] = v;
          else if (mode == 1) atomicAdd(&C[o], v);
          else if (mode == 4) {
            C[o] = v;
            u16 hh = f2bf(v); Chp[o] = hh; Clp[o] = f2bf(v - bfu(hh));
          } else {
            u16 hh = f2bf(v); Chp[o] = hh; Clp[o] = f2bf(v - bfu(hh));
          }
        }
      }
    }
  }
}

// MFMA attention: grid 128 = (g 8, h 4, tq 4), 256 threads (4 waves).
__global__ __launch_bounds__(256) void attn_mfma(
    const u16* __restrict__ Qh, const u16* __restrict__ Ql,
    const u16* __restrict__ Vth, const u16* __restrict__ Vtl,
    u16* __restrict__ Oh, u16* __restrict__ Ol) {
  int tq = blockIdx.x & 3;
  int h = (blockIdx.x >> 2) & 3;
  int g = blockIdx.x >> 4;
  int tid = threadIdx.x;
  int w = tid >> 6, lane = tid & 63, quad = lane >> 4, lm = lane & 15;
  __shared__ float S[32][132];

  f32x4 sacc[2][2] = {};
#pragma unroll
  for (int ks = 0; ks < 4; ++ks) {
    bf16x8 qh[2], ql[2];
#pragma unroll
    for (int mi = 0; mi < 2; ++mi) {
      size_t qi = (size_t)(g * 128 + tq * 32 + mi * 16 + lm) * 1536 + h * 128 + ks * 32 + quad * 8;
      qh[mi] = *(const bf16x8*)(Qh + qi);
      ql[mi] = *(const bf16x8*)(Ql + qi);
    }
#pragma unroll
    for (int ni = 0; ni < 2; ++ni) {
      size_t kix = (size_t)(g * 128 + w * 32 + ni * 16 + lm) * 1536 + 512 + h * 128 + ks * 32 + quad * 8;
      bf16x8 kh = *(const bf16x8*)(Qh + kix);
      bf16x8 kl = *(const bf16x8*)(Ql + kix);
#pragma unroll
      for (int mi = 0; mi < 2; ++mi) {
        sacc[mi][ni] = __builtin_amdgcn_mfma_f32_16x16x32_bf16(qh[mi], kh, sacc[mi][ni], 0, 0, 0);
        sacc[mi][ni] = __builtin_amdgcn_mfma_f32_16x16x32_bf16(ql[mi], kh, sacc[mi][ni], 0, 0, 0);
        sacc[mi][ni] = __builtin_amdgcn_mfma_f32_16x16x32_bf16(qh[mi], kl, sacc[mi][ni], 0, 0, 0);
      }
    }
  }
  const float scale = 0.08838834764831845f;
#pragma unroll
  for (int mi = 0; mi < 2; ++mi)
#pragma unroll
    for (int ni = 0; ni < 2; ++ni)
#pragma unroll
      for (int r = 0; r < 4; ++r)
        S[mi * 16 + quad * 4 + r][w * 32 + ni * 16 + lm] = sacc[mi][ni][r] * scale;
  __syncthreads();

  {
    int row = tid >> 3, j = tid & 7;
    float* sp = &S[row][j * 16];
    float v[16];
    *(float4*)(v) = *(float4*)(sp);
    *(float4*)(v + 4) = *(float4*)(sp + 4);
    *(float4*)(v + 8) = *(float4*)(sp + 8);
    *(float4*)(v + 12) = *(float4*)(sp + 12);
    float mx = v[0];
#pragma unroll
    for (int i = 1; i < 16; ++i) mx = fmaxf(mx, v[i]);
    mx = fmaxf(mx, __shfl_xor(mx, 1));
    mx = fmaxf(mx, __shfl_xor(mx, 2));
    mx = fmaxf(mx, __shfl_xor(mx, 4));
    float sum = 0.f;
#pragma unroll
    for (int i = 0; i < 16; ++i) { v[i] = expf(v[i] - mx); sum += v[i]; }
    sum += __shfl_xor(sum, 1);
    sum += __shfl_xor(sum, 2);
    sum += __shfl_xor(sum, 4);
    float inv = 1.f / sum;
#pragma unroll
    for (int i = 0; i < 16; ++i) v[i] *= inv;
    *(float4*)(sp) = *(float4*)(v);
    *(float4*)(sp + 4) = *(float4*)(v + 4);
    *(float4*)(sp + 8) = *(float4*)(v + 8);
    *(float4*)(sp + 12) = *(float4*)(v + 12);
  }
  __syncthreads();

  f32x4 oacc[2][2] = {};
#pragma unroll
  for (int ks = 0; ks < 4; ++ks) {
    bf16x8 ph[2], pl[2];
#pragma unroll
    for (int mi = 0; mi < 2; ++mi) {
      float pv[8];
      const float* srow = &S[mi * 16 + lm][ks * 32 + quad * 8];
      *(float4*)(pv) = *(const float4*)srow;
      *(float4*)(pv + 4) = *(const float4*)(srow + 4);
      bf16x8 hh, ll;
#pragma unroll
      for (int i = 0; i < 8; ++i) {
        u16 hb = f2bf(pv[i]);
        hh[i] = (short)hb;
        ll[i] = (short)f2bf(pv[i] - bfu(hb));
      }
      ph[mi] = hh; pl[mi] = ll;
    }
#pragma unroll
    for (int ni = 0; ni < 2; ++ni) {
      size_t vi = (size_t)(g * 512 + h * 128 + w * 32 + ni * 16 + lm) * 128 + ks * 32 + quad * 8;
      bf16x8 vh = *(const bf16x8*)(Vth + vi);
      bf16x8 vl = *(const bf16x8*)(Vtl + vi);
#pragma unroll
      for (int mi = 0; mi < 2; ++mi) {
        oacc[mi][ni] = __builtin_amdgcn_mfma_f32_16x16x32_bf16(ph[mi], vh, oacc[mi][ni], 0, 0, 0);
        oacc[mi][ni] = __builtin_amdgcn_mfma_f32_16x16x32_bf16(pl[mi], vh, oacc[mi][ni], 0, 0, 0);
        oacc[mi][ni] = __builtin_amdgcn_mfma_f32_16x16x32_bf16(ph[mi], vl, oacc[mi][ni], 0, 0, 0);
      }
    }
  }
#pragma unroll
  for (int mi = 0; mi < 2; ++mi)
#pragma unroll
    for (int ni = 0; ni < 2; ++ni)
#pragma unroll
      for (int r = 0; r < 4; ++r) {
        int t = tq * 32 + mi * 16 + quad * 4 + r;
        int d = w * 32 + ni * 16 + lm;
        size_t o = (size_t)(g * 128 + t) * 512 + h * 128 + d;
        float val = oacc[mi][ni][r];
        u16 hb = f2bf(val);
        Oh[o] = hb;
        Ol[o] = f2bf(val - bfu(hb));
      }
}

// LN fp32 in -> optional fp32 out (in-place safe) + hi/lo planes.
__global__ __launch_bounds__(256) void ln2(
    const float* __restrict__ in, float* __restrict__ outf,
    u16* __restrict__ oh, u16* __restrict__ ol,
    const void* __restrict__ w, const void* __restrict__ b, size_t wboff,
    const void* __restrict__ pe_w) {
  const int isbf = getbf(pe_w);
  const int D = 512;
  int row = blockIdx.x;
  __shared__ float sbuf[8];
  int i0 = threadIdx.x, i1 = threadIdx.x + 256;
  float v0 = in[(size_t)row * D + i0];
  float v1 = in[(size_t)row * D + i1];
  float mean = block_sum(v0 + v1, sbuf) / 512.f;
  float d0 = v0 - mean, d1 = v1 - mean;
  float var = block_sum(d0 * d0 + d1 * d1, sbuf) / 512.f;
  float inv = 1.0f / sqrtf(var + 1e-12f);
  float r0 = ldin(w, wboff + i0, isbf) * d0 * inv + ldin(b, wboff + i0, isbf);
  float r1 = ldin(w, wboff + i1, isbf) * d1 * inv + ldin(b, wboff + i1, isbf);
  size_t o0 = (size_t)row * D + i0, o1 = (size_t)row * D + i1;
  if (outf) { outf[o0] = r0; outf[o1] = r1; }
  u16 h0 = f2bf(r0); oh[o0] = h0; ol[o0] = f2bf(r0 - bfu(h0));
  u16 h1 = f2bf(r1); oh[o1] = h1; ol[o1] = f2bf(r1 - bfu(h1));
}

// proj (blocks 0..1023) + gram (blocks 1024..1048), merged.
__global__ __launch_bounds__(64) void projgram(const float* __restrict__ qkb,
                                               const void* __restrict__ ce,
                                               float* __restrict__ ck, float* __restrict__ G,
                                               const void* __restrict__ pe_w) {
  const int isbf = getbf(pe_w);
  if (blockIdx.x < 1024) {
    int row = blockIdx.x;
#pragma unroll
    for (int c = 0; c < 5; ++c) {
      float acc = 0.f;
      for (int d = threadIdx.x; d < 512; d += 64)
        acc = fmaf(qkb[(size_t)row * 512 + d], ldin(ce, (size_t)c * 512 + d, isbf), acc);
      acc = wave_sum(acc);
      if (threadIdx.x == 0) ck[row * 5 + c] = acc;
    }
  } else {
    int i = blockIdx.x - 1024;
    int c = i / 5, c2 = i % 5;
    float acc = 0.f;
    for (int d = threadIdx.x; d < 512; d += 64)
      acc = fmaf(ldin(ce, (size_t)c * 512 + d, isbf), ldin(ce, (size_t)c2 * 512 + d, isbf), acc);
    acc = wave_sum(acc);
    if (threadIdx.x == 0) G[i] = acc;
  }
}

// Merged sim-mid: blocks 0..63 compute relation term R (t-major, coalesced);
// blocks 64..79 compute S = q@k^T (batched over b, 64x64 MFMA tiles, store).
__global__ __launch_bounds__(256) void sim_mid(
    const void* __restrict__ aq, const void* __restrict__ qa,
    const float* __restrict__ ck, const float* __restrict__ G,
    const u16* __restrict__ Qh, const u16* __restrict__ Ql,
    float* __restrict__ R, float* __restrict__ Sbuf,
    const void* __restrict__ pe_w) {
  const int isbf = getbf(pe_w);
  int tid = threadIdx.x;
  if (blockIdx.x < 64) {
    // ---- relation term (prep_rel body) ----
    int bx = blockIdx.x;
    int t0 = (bx & 3) * 32;
    int s0 = ((bx >> 2) & 3) * 32;
    int b = bx >> 4;
    __shared__ float aqs[32][164];  // [s][t*5+c], pad->4 mod 32 banks
    __shared__ float Gs[25];
    __shared__ float kcs[32][5];
    __shared__ float qcs[32][5];
    for (int i = tid; i < 5120; i += 256) {
      int s = i / 160, r = i % 160;
      aqs[s][r] = ldin(aq, ((size_t)(b * 128 + s0 + s) * 128 + t0) * 5 + r, isbf);
    }
    if (tid < 25) Gs[tid] = G[tid];
    for (int i = tid; i < 160; i += 256)
      kcs[i / 5][i % 5] = ck[(size_t)(512 + b * 128 + s0 + i / 5) * 5 + i % 5];
    for (int i = tid; i < 160; i += 256)
      qcs[i / 5][i % 5] = ck[(size_t)(b * 128 + t0 + i / 5) * 5 + i % 5];
    __syncthreads();
    for (int i = tid; i < 1024; i += 256) {
      int t = i >> 5, s = i & 31;
      size_t qoff = ((size_t)(b * 128 + t0 + t) * 128 + s0 + s) * 5;
      float r = 0.f;
#pragma unroll
      for (int c = 0; c < 5; ++c) {
        float ga = 0.f;
#pragma unroll
        for (int c2 = 0; c2 < 5; ++c2) ga = fmaf(Gs[c * 5 + c2], aqs[s][t * 5 + c2], ga);
        r = fmaf(ldin(qa, qoff + c, isbf), kcs[s][c] + ga, r);
        r = fmaf(aqs[s][t * 5 + c], qcs[t][c], r);
      }
      R[(size_t)(b * 128 + t0 + t) * 128 + s0 + s] = r;
    }
  } else {
    // ---- S = q@k^T (64x64 MFMA tile, same fragment scheme as gemm_hl) ----
    int idx = blockIdx.x - 64;
    int bxg = idx & 1, byg = idx >> 1;   // 2 col-tiles x 8 row-tiles
    int row0 = byg * 64, col0 = bxg * 64;
    size_t wrow0 = 512 + (size_t)(byg >> 1) * 128 + col0;
    __shared__ __align__(16) u16 sAh[64][72];
    __shared__ __align__(16) u16 sAl[64][72];
    __shared__ __align__(16) u16 sBh[64][72];
    __shared__ __align__(16) u16 sBl[64][72];
    int wid = tid >> 6, lane = tid & 63, quad = lane >> 4, lm = lane & 15;
    int mrow = (wid & 1) * 32, ncol = (wid >> 1) * 32;
    f32x4 acc[2][2] = {};
    int sr = tid >> 2, sc = (tid & 3) * 16;
    for (int k0 = 0; k0 < 512; k0 += 64) {
      const u16* p;
      p = Qh + (size_t)(row0 + sr) * 512 + k0 + sc;
      uint4 a0 = *(const uint4*)p, a1 = *(const uint4*)(p + 8);
      p = Ql + (size_t)(row0 + sr) * 512 + k0 + sc;
      uint4 a2 = *(const uint4*)p, a3 = *(const uint4*)(p + 8);
      p = Qh + (wrow0 + sr) * 512 + k0 + sc;
      uint4 w0 = *(const uint4*)p, w1 = *(const uint4*)(p + 8);
      p = Ql + (wrow0 + sr) * 512 + k0 + sc;
      uint4 w2 = *(const uint4*)p, w3 = *(const uint4*)(p + 8);
      __syncthreads();
      *(uint4*)&sAh[sr][sc] = a0; *(uint4*)&sAh[sr][sc + 8] = a1;
      *(uint4*)&sAl[sr][sc] = a2; *(uint4*)&sAl[sr][sc + 8] = a3;
      *(uint4*)&sBh[sr][sc] = w0; *(uint4*)&sBh[sr][sc + 8] = w1;
      *(uint4*)&sBl[sr][sc] = w2; *(uint4*)&sBl[sr][sc + 8] = w3;
      __syncthreads();
#pragma unroll
      for (int ks = 0; ks < 2; ++ks) {
        bf16x8 ah[2], al[2], wh[2], wl[2];
#pragma unroll
        for (int mi = 0; mi < 2; ++mi) {
          ah[mi] = *(const bf16x8*)&sAh[mrow + mi * 16 + lm][ks * 32 + quad * 8];
          al[mi] = *(const bf16x8*)&sAl[mrow + mi * 16 + lm][ks * 32 + quad * 8];
        }
#pragma unroll
        for (int ni = 0; ni < 2; ++ni) {
          wh[ni] = *(const bf16x8*)&sBh[ncol + ni * 16 + lm][ks * 32 + quad * 8];
          wl[ni] = *(const bf16x8*)&sBl[ncol + ni * 16 + lm][ks * 32 + quad * 8];
        }
#pragma unroll
        for (int mi = 0; mi < 2; ++mi)
#pragma unroll
          for (int ni = 0; ni < 2; ++ni) {
            acc[mi][ni] = __builtin_amdgcn_mfma_f32_16x16x32_bf16(ah[mi], wh[ni], acc[mi][ni], 0, 0, 0);
            acc[mi][ni] = __builtin_amdgcn_mfma_f32_16x16x32_bf16(al[mi], wh[ni], acc[mi][ni], 0, 0, 0);
            acc[mi][ni] = __builtin_amdgcn_mfma_f32_16x16x32_bf16(ah[mi], wl[ni], acc[mi][ni], 0, 0, 0);
          }
      }
    }
#pragma unroll
    for (int mi = 0; mi < 2; ++mi)
#pragma unroll
      for (int ni = 0; ni < 2; ++ni) {
        int colg = col0 + ncol + ni * 16 + lm;
#pragma unroll
        for (int r = 0; r < 4; ++r) {
          int rowg = row0 + mrow + mi * 16 + quad * 4 + r;
          Sbuf[(size_t)rowg * 128 + colg] = acc[mi][ni][r];
        }
      }
  }
}

// Row softmax + sharpen over S+R; writes transposed PT[b][s][t].
// grid 512 = (b*128+t), 128 threads (s).
__global__ __launch_bounds__(128) void softmax_rel(
    const float* __restrict__ Sbuf, const float* __restrict__ R,
    float* __restrict__ PT) {
  int row = blockIdx.x;          // b*128 + t
  int b = row >> 7, t = row & 127;
  int s = threadIdx.x;
  __shared__ float sbuf[8];
  size_t o = (size_t)row * 128 + s;
  float sc = Sbuf[o] + R[o];
  float mx = block_max(sc, sbuf);
  float e = expf(sc - mx);
  float ssum = block_sum(e, sbuf);
  float p = e / ssum;
  float mx2 = block_max(p, sbuf);
  float e2 = expf(1000.f * (p - mx2));
  float s2 = block_sum(e2, sbuf);
  float pf = fminf(fmaxf(e2 / s2, 0.f), 1.f);
  PT[(size_t)(b * 128 + s) * 128 + t] = pf;
}

// Pbar[b,s] = sum_t PT[b,s,t]; pabarS[bs][c] = sum_t PT[b,s,t]*aq[b,s,t,c].
// grid 512 = (b*128+s), 64 threads (2 t's each). All reads coalesced; no atomics.
__global__ __launch_bounds__(64) void pbar2(
    const float* __restrict__ PT, const void* __restrict__ aq,
    float* __restrict__ Pbar, float* __restrict__ pabarS,
    const void* __restrict__ pe_w) {
  const int isbf = getbf(pe_w);
  int bs = blockIdx.x;           // b*128 + s
  int lane = threadIdx.x;
  int t0 = lane * 2;
  float2 pt = *(const float2*)(PT + (size_t)bs * 128 + t0);
  size_t ao = ((size_t)bs * 128 + t0) * 5;
  float psum = pt.x + pt.y;
  float pac[5];
#pragma unroll
  for (int c = 0; c < 5; ++c)
    pac[c] = pt.x * ldin(aq, ao + c, isbf) + pt.y * ldin(aq, ao + 5 + c, isbf);
  psum = wave_sum(psum);
#pragma unroll
  for (int c = 0; c < 5; ++c) pac[c] = wave_sum(pac[c]);
  if (lane == 0) {
    Pbar[bs] = psum;
#pragma unroll
    for (int c = 0; c < 5; ++c) pabarS[(size_t)bs * 5 + c] = pac[c];
  }
}

// mean-over-t + classifier from Pbar/pabarS (coalesced k reads only).
__global__ __launch_bounds__(512) void meancls(
    const float* __restrict__ qkb, const float* __restrict__ Pbar,
    const float* __restrict__ pabarS,
    const void* __restrict__ ce, const void* __restrict__ clsw, const void* __restrict__ clsb,
    void* __restrict__ out, const void* __restrict__ pe_w) {
  const int isbf = getbf(pe_w);
  int b = blockIdx.x;
  int tid = threadIdx.x;
  __shared__ float Ps[128];
  __shared__ float pas[5];
  __shared__ float xm[512];
  __shared__ float sbuf[8];
  if (tid < 5) pas[tid] = 0.f;
  __syncthreads();
  if (tid < 128) {
    Ps[tid] = Pbar[b * 128 + tid];
    const float* ps = pabarS + ((size_t)(b * 128 + tid)) * 5;
    float pac[5] = {ps[0], ps[1], ps[2], ps[3], ps[4]};
#pragma unroll
    for (int c = 0; c < 5; ++c) {
      float v = wave_sum(pac[c]);
      if ((tid & 63) == 0) atomicAdd(&pas[c], v);
    }
  }
  __syncthreads();
  int d = tid;
  const float* k = qkb + (size_t)(512 + b * 128) * 512 + d;
  float acc = 0.f;
  for (int s = 0; s < 128; ++s) acc = fmaf(Ps[s], k[(size_t)s * 512], acc);
#pragma unroll
  for (int c = 0; c < 5; ++c) acc = fmaf(pas[c], ldin(ce, (size_t)c * 512 + d, isbf), acc);
  acc *= (1.f / 128.f);
  xm[d] = acc;
  __syncthreads();
  for (int j = 0; j < 3; ++j) {
    float v = block_sum(xm[d] * ldin(clsw, (size_t)d * 3 + j, isbf), sbuf);
    if (d == 0) {
      float val = v + ldin(clsb, j, isbf);
      if (isbf) ((u16*)out)[b * 3 + j] = f2bf(val);
      else ((float*)out)[b * 3 + j] = val;
    }
    __syncthreads();
  }
}

// ===========================================================================
// fallback round-6 kernels (used only if ws too small for fast path)
// ===========================================================================

__global__ __launch_bounds__(256) void gemm_mfma(
    const float* __restrict__ A, const void* __restrict__ W, size_t woff,
    const void* __restrict__ bias, size_t boff,
    float* __restrict__ C, int M, int N, int K, int act, int addto,
    const int* __restrict__ dflag) {
  const int isbf = *dflag;
  __shared__ __align__(16) u16 Ah[64][40];
  __shared__ __align__(16) u16 Al[64][40];
  __shared__ __align__(16) u16 Wh[64][40];
  __shared__ __align__(16) u16 Wl[64][40];
  int tid = threadIdx.x;
  int row0 = blockIdx.y * 64, col0 = blockIdx.x * 64;
  int wid = tid >> 6, lane = tid & 63;
  int quad = lane >> 4, lm = lane & 15;
  int mrow = (wid & 1) * 32, ncol = (wid >> 1) * 32;
  f32x4 acc[2][2] = {};
  int ar = tid >> 2, akc = (tid & 3) * 8;
  int bk = tid >> 3, bn0 = (tid & 7) * 8;
  for (int k0 = 0; k0 < K; k0 += 32) {
    const float* ap = A + (size_t)(row0 + ar) * K + k0 + akc;
    float av[8];
    *(float4*)(av) = *(const float4*)ap;
    *(float4*)(av + 4) = *(const float4*)(ap + 4);
    unsigned hp[4], lp[4];
#pragma unroll
    for (int j = 0; j < 4; ++j) {
      u16 h0 = f2bf(av[2 * j]);
      u16 h1 = f2bf(av[2 * j + 1]);
      u16 l0 = f2bf(av[2 * j] - bfu(h0));
      u16 l1 = f2bf(av[2 * j + 1] - bfu(h1));
      hp[j] = (unsigned)h0 | ((unsigned)h1 << 16);
      lp[j] = (unsigned)l0 | ((unsigned)l1 << 16);
    }
    *(uint4*)&Ah[ar][akc] = make_uint4(hp[0], hp[1], hp[2], hp[3]);
    *(uint4*)&Al[ar][akc] = make_uint4(lp[0], lp[1], lp[2], lp[3]);
    float wv[8];
    size_t welem = woff + (size_t)(k0 + bk) * N + col0 + bn0;
    if (isbf) {
      const u16* wp = (const u16*)W + welem;
      uint4 raw = *(const uint4*)wp;
      wv[0] = bfu((u16)(raw.x & 0xFFFF)); wv[1] = bfu((u16)(raw.x >> 16));
      wv[2] = bfu((u16)(raw.y & 0xFFFF)); wv[3] = bfu((u16)(raw.y >> 16));
      wv[4] = bfu((u16)(raw.z & 0xFFFF)); wv[5] = bfu((u16)(raw.z >> 16));
      wv[6] = bfu((u16)(raw.w & 0xFFFF)); wv[7] = bfu((u16)(raw.w >> 16));
    } else {
      const float* wp = (const float*)W + welem;
      *(float4*)(wv) = *(const float4*)wp;
      *(float4*)(wv + 4) = *(const float4*)(wp + 4);
    }
#pragma unroll
    for (int i = 0; i < 8; ++i) {
      u16 h = f2bf(wv[i]);
      u16 l = f2bf(wv[i] - bfu(h));
      Wh[bn0 + i][bk] = h;
      Wl[bn0 + i][bk] = l;
    }
    __syncthreads();
#pragma unroll
    for (int mi = 0; mi < 2; ++mi) {
      bf16x8 ah = *(const bf16x8*)&Ah[mrow + mi * 16 + lm][quad * 8];
      bf16x8 al = *(const bf16x8*)&Al[mrow + mi * 16 + lm][quad * 8];
#pragma unroll
      for (int ni = 0; ni < 2; ++ni) {
        bf16x8 wh = *(const bf16x8*)&Wh[ncol + ni * 16 + lm][quad * 8];
        bf16x8 wl = *(const bf16x8*)&Wl[ncol + ni * 16 + lm][quad * 8];
        acc[mi][ni] = __builtin_amdgcn_mfma_f32_16x16x32_bf16(ah, wh, acc[mi][ni], 0, 0, 0);
        acc[mi][ni] = __builtin_amdgcn_mfma_f32_16x16x32_bf16(al, wh, acc[mi][ni], 0, 0, 0);
        acc[mi][ni] = __builtin_amdgcn_mfma_f32_16x16x32_bf16(ah, wl, acc[mi][ni], 0, 0, 0);
      }
    }
    __syncthreads();
  }
#pragma unroll
  for (int mi = 0; mi < 2; ++mi) {
#pragma unroll
    for (int ni = 0; ni < 2; ++ni) {
      int colg = col0 + ncol + ni * 16 + lm;
      float bv = ldin(bias, boff + colg, isbf);
#pragma unroll
      for (int r = 0; r < 4; ++r) {
        int rowg = row0 + mrow + mi * 16 + quad * 4 + r;
        float v = acc[mi][ni][r] + bv;
        if (act) v = v * 0.5f * (1.f + erff(v * 0.70710678118654752f));
        size_t o = (size_t)rowg * N + colg;
        if (addto) C[o] += v; else C[o] = v;
      }
    }
  }
}

__global__ __launch_bounds__(256) void emb_ln_kernel(const void* __restrict__ emb,
                                                     const void* __restrict__ pos,
                                                     const void* __restrict__ w,
                                                     const void* __restrict__ b,
                                                     float* __restrict__ out, int T, int D,
                                                     const int* __restrict__ dflag) {
  const int isbf = *dflag;
  int row = blockIdx.x;
  int t = row % T;
  __shared__ float sbuf[8];
  int i0 = threadIdx.x, i1 = threadIdx.x + 256;
  float v0 = ldin(emb, (size_t)row * D + i0, isbf) + ldin(pos, (size_t)t * D + i0, isbf);
  float v1 = ldin(emb, (size_t)row * D + i1, isbf) + ldin(pos, (size_t)t * D + i1, isbf);
  float mean = block_sum(v0 + v1, sbuf) / (float)D;
  float d0 = v0 - mean, d1 = v1 - mean;
  float var = block_sum(d0 * d0 + d1 * d1, sbuf) / (float)D;
  float inv = 1.0f / sqrtf(var + 1e-12f);
  out[(size_t)row * D + i0] = ldin(w, i0, isbf) * d0 * inv + ldin(b, i0, isbf);
  out[(size_t)row * D + i1] = ldin(w, i1, isbf) * d1 * inv + ldin(b, i1, isbf);
}

__global__ __launch_bounds__(256) void ln_kernel(const float* __restrict__ in, float* __restrict__ out,
                                                 const void* __restrict__ w, const void* __restrict__ b,
                                                 size_t wboff, int D, const int* __restrict__ dflag) {
  const int isbf = *dflag;
  int row = blockIdx.x;
  __shared__ float sbuf[8];
  int i0 = threadIdx.x, i1 = threadIdx.x + 256;
  float v0 = in[(size_t)row * D + i0];
  float v1 = in[(size_t)row * D + i1];
  float mean = block_sum(v0 + v1, sbuf) / (float)D;
  float d0 = v0 - mean, d1 = v1 - mean;
  float var = block_sum(d0 * d0 + d1 * d1, sbuf) / (float)D;
  float inv = 1.0f / sqrtf(var + 1e-12f);
  out[(size_t)row * D + i0] = ldin(w, wboff + i0, isbf) * d0 * inv + ldin(b, wboff + i0, isbf);
  out[(size_t)row * D + i1] = ldin(w, wboff + i1, isbf) * d1 * inv + ldin(b, wboff + i1, isbf);
}

__global__ __launch_bounds__(128) void attn_kernel(const float* __restrict__ q, const float* __restrict__ k,
                                                   const float* __restrict__ v, float* __restrict__ o,
                                                   int B, int H, int T, int dk) {
  int t = blockIdx.x % T;
  int h = (blockIdx.x / T) % H;
  int b = blockIdx.x / (T * H);
  int D = H * dk;
  int tid = threadIdx.x;
  __shared__ float qs[128];
  __shared__ float ps[128];
  __shared__ float sbuf[8];
  qs[tid] = q[(size_t)(b * T + t) * D + h * dk + tid];
  __syncthreads();
  const float* krow = k + (size_t)(b * T + tid) * D + h * dk;
  float sc = 0.f;
#pragma unroll 8
  for (int d = 0; d < 128; ++d) sc = fmaf(qs[d], krow[d], sc);
  sc *= 0.08838834764831845f;
  float mx = block_max(sc, sbuf);
  float e = expf(sc - mx);
  float s = block_sum(e, sbuf);
  ps[tid] = e / s;
  __syncthreads();
  float acc = 0.f;
  for (int s2 = 0; s2 < 128; ++s2)
    acc = fmaf(ps[s2], v[(size_t)(b * T + s2) * D + h * dk + tid], acc);
  o[(size_t)(b * T + t) * D + h * dk + tid] = acc;
}

__global__ __launch_bounds__(64) void proj_ce_kernel(const float* __restrict__ q,
                                                     const void* __restrict__ ce,
                                                     float* __restrict__ out, int D, int NC,
                                                     const int* __restrict__ dflag) {
  const int isbf = *dflag;
  int row = blockIdx.x;
  for (int c = 0; c < NC; ++c) {
    float acc = 0.f;
    for (int d = threadIdx.x; d < D; d += 64)
      acc = fmaf(q[(size_t)row * D + d], ldin(ce, (size_t)c * D + d, isbf), acc);
    acc = wave_sum(acc);
    if (threadIdx.x == 0) out[row * NC + c] = acc;
  }
}

__global__ __launch_bounds__(64) void gram_kernel(const void* __restrict__ ce,
                                                  float* __restrict__ G, int D, int NC,
                                                  const int* __restrict__ dflag) {
  const int isbf = *dflag;
  int c = blockIdx.x / NC, c2 = blockIdx.x % NC;
  float acc = 0.f;
  for (int d = threadIdx.x; d < D; d += 64)
    acc = fmaf(ldin(ce, (size_t)c * D + d, isbf), ldin(ce, (size_t)c2 * D + d, isbf), acc);
  acc = wave_sum(acc);
  if (threadIdx.x == 0) G[blockIdx.x] = acc;
}

__global__ __launch_bounds__(128) void sim_scores_kernel(
    const float* __restrict__ q, const float* __restrict__ k, const void* __restrict__ qa,
    const void* __restrict__ aq, const float* __restrict__ qc, const float* __restrict__ kc,
    const float* __restrict__ G, float* __restrict__ p_out, float* __restrict__ pa_out,
    int B, int T1, int T2, int D, int NC, const int* __restrict__ dflag) {
  const int isbf = *dflag;
  int t = blockIdx.x % T1;
  int b = blockIdx.x / T1;
  int s = threadIdx.x;
  __shared__ float qs[512];
  __shared__ float Gs[25];
  __shared__ float qcs[5];
  __shared__ float sbuf[8];
  for (int i = threadIdx.x; i < D; i += 128) qs[i] = q[(size_t)(b * T1 + t) * D + i];
  if (threadIdx.x < NC * NC) Gs[threadIdx.x] = G[threadIdx.x];
  if (threadIdx.x < NC) qcs[threadIdx.x] = qc[(b * T1 + t) * NC + threadIdx.x];
  __syncthreads();
  const float* krow = k + (size_t)(b * T2 + s) * D;
  float sc = 0.f;
#pragma unroll 8
  for (int d = 0; d < 512; ++d) sc = fmaf(qs[d], krow[d], sc);
  float qav[5], aqv[5];
#pragma unroll
  for (int c = 0; c < 5; ++c) {
    qav[c] = ldin(qa, (size_t)((b * T1 + t) * T2 + s) * NC + c, isbf);
    aqv[c] = ldin(aq, (size_t)((b * T2 + s) * T1 + t) * NC + c, isbf);
  }
#pragma unroll
  for (int c = 0; c < 5; ++c) {
    sc = fmaf(aqv[c], qcs[c], sc);
    sc = fmaf(qav[c], kc[(b * T2 + s) * NC + c], sc);
#pragma unroll
    for (int c2 = 0; c2 < 5; ++c2) sc = fmaf(qav[c] * Gs[c * 5 + c2], aqv[c2], sc);
  }
  float mx = block_max(sc, sbuf);
  float e = expf(sc - mx);
  float ssum = block_sum(e, sbuf);
  float p = e / ssum;
  float mx2 = block_max(p, sbuf);
  float e2 = expf(1000.f * (p - mx2));
  float s2 = block_sum(e2, sbuf);
  float pf = fminf(fmaxf(e2 / s2, 0.f), 1.f);
  p_out[(size_t)(b * T1 + t) * T2 + s] = pf;
#pragma unroll
  for (int c = 0; c < 5; ++c) {
    float pc = block_sum(pf * aqv[c], sbuf);
    if (threadIdx.x == 0) pa_out[(b * T1 + t) * NC + c] = pc;
  }
}

__global__ __launch_bounds__(512) void sim_x_kernel(const float* __restrict__ p, const float* __restrict__ k,
                                                    const float* __restrict__ pa,
                                                    const void* __restrict__ ce,
                                                    float* __restrict__ x, int B, int T1, int T2, int D, int NC,
                                                    const int* __restrict__ dflag) {
  const int isbf = *dflag;
  int t = blockIdx.x % T1;
  int b = blockIdx.x / T1;
  int d = threadIdx.x;
  __shared__ float ps[128];
  __shared__ float pav[5];
  if (threadIdx.x < T2) ps[threadIdx.x] = p[(size_t)(b * T1 + t) * T2 + threadIdx.x];
  if (threadIdx.x < NC) pav[threadIdx.x] = pa[(b * T1 + t) * NC + threadIdx.x];
  __syncthreads();
  float acc = 0.f;
  for (int s = 0; s < 128; ++s) acc = fmaf(ps[s], k[(size_t)(b * T2 + s) * D + d], acc);
#pragma unroll
  for (int c = 0; c < 5; ++c) acc = fmaf(pav[c], ldin(ce, (size_t)c * D + d, isbf), acc);
  x[(size_t)(b * T1 + t) * D + d] = acc;
}

__global__ __launch_bounds__(512) void mean_kernel(const float* __restrict__ x, float* __restrict__ xm,
                                                   int T, int D) {
  int b = blockIdx.x;
  int d = threadIdx.x;
  float acc = 0.f;
  for (int t = 0; t < T; ++t) acc += x[(size_t)(b * T + t) * D + d];
  xm[(size_t)b * D + d] = acc / (float)T;
}

__global__ __launch_bounds__(64) void cls_kernel(const float* __restrict__ xm,
                                                 const void* __restrict__ w,
                                                 const void* __restrict__ bias,
                                                 void* __restrict__ out, int D, int NO,
                                                 const int* __restrict__ dflag) {
  const int isbf = *dflag;
  int j = blockIdx.x % NO;
  int b = blockIdx.x / NO;
  float acc = 0.f;
  for (int d = threadIdx.x; d < D; d += 64)
    acc = fmaf(xm[(size_t)b * D + d], ldin(w, (size_t)d * NO + j, isbf), acc);
  acc = wave_sum(acc);
  if (threadIdx.x == 0) {
    float val = acc + ldin(bias, j, isbf);
    if (isbf) ((__hip_bfloat16*)out)[b * NO + j] = __float2bfloat16(val);
    else ((float*)out)[b * NO + j] = val;
  }
}

// ===========================================================================
extern "C" void kernel_launch(void* const* d_in, const int* in_sizes, int n_in,
                              void* d_out, int out_size, void* d_ws, size_t ws_size,
                              hipStream_t stream) {
  const int B = 4, T = 128, D = 512, H = 4, NL = 4, DFF = 2048, NC = 5;
  const void *q_emb = d_in[0], *a_emb = d_in[1], *qa = d_in[2], *aqr = d_in[3],
             *ce = d_in[4], *pos = d_in[5], *pe_w = d_in[6], *pe_b = d_in[7],
             *Wq = d_in[8], *bq = d_in[9], *Wk = d_in[10], *bk = d_in[11],
             *Wv = d_in[12], *bv = d_in[13], *Wo = d_in[14], *bo = d_in[15],
             *ff1w = d_in[16], *ff1b = d_in[17], *ff2w = d_in[18], *ff2b = d_in[19],
             *lnin_w = d_in[20], *lnin_b = d_in[21], *lnout_w = d_in[22], *lnout_b = d_in[23],
             *simWq = d_in[24], *simbq = d_in[25], *simWk = d_in[26], *simbk = d_in[27],
             *clsw = d_in[28], *clsb = d_in[29];

  const size_t REQ = 83000000ull;  // poison-fill showed ws ~268 MB; fallback if smaller
  if (ws_size >= REQ) {
    // -------- FAST PATH --------
    char* base = (char*)d_ws;
    float* x = (float*)(base + 0);
    u16* xch = (u16*)(base + 2097152);
    u16* xcl = (u16*)(base + 3145728);
    u16* qkvh = (u16*)(base + 4194304);
    u16* qkvl = (u16*)(base + 7340032);
    u16* ffch = (u16*)(base + 10485760);
    u16* ffcl = (u16*)(base + 14680064);
    u16* Vth = (u16*)(base + 18874368);
    u16* Vtl = (u16*)(base + 19922944);
    float* qkb = (float*)(base + 20971520);        // [1024][512] fp32 sim q|k
    u16* qsh = (u16*)(base + 23068672);            // sim q|k hi plane [1024][512]
    u16* qsl = (u16*)(base + 24117248);            // lo
    float* ck = (float*)(base + 25165824);         // [1024][5]
    float* Gbuf = (float*)(base + 25186304);       // 25
    float* Pbar = (float*)(base + 25190400);       // [4][128]
    u16* wh = (u16*)(base + 26214400);             // 13,107,200 elems
    u16* wl = (u16*)(base + 52428800);
    float* Sbuf = (float*)(base + 79691776);       // [4][128][128] scores (256 KB)
    float* R = (float*)(base + 79953920);          // [4][128][128] relation (256 KB)
    float* PT = (float*)(base + 80216064);         // [4][128][128] sharpened P^T (256 KB)
    float* pabarS = (float*)(base + 80478208);     // [512][5] partials (10 KB)
    // wAll layout per layer l (base l*3145728): QKVO T [2048][512] | FF1 T | FF2 T [512][2048]
    // sim at +12582912: [1024][512]

    convT_all<<<dim3(16, 16, 54), 256, 0, stream>>>(Wq, Wk, Wv, Wo, ff1w, ff2w,
                                                    simWq, simWk, wh, wl,
                                                    q_emb, a_emb, pos, pe_w, pe_b,
                                                    x, xch, xcl);

    for (int l = 0; l < NL; ++l) {
      size_t wbase = (size_t)l * 3145728, bD = (size_t)l * D;
      gemm_hl<<<dim3(24, 16, 1), 256, 0, stream>>>(xch, xcl, 512, wh + wbase, wl + wbase, 512,
                                                   bq, bk, bv, bD, bD, bD, 9,
                                                   nullptr, qkvh, qkvl, Vth, Vtl, 1536,
                                                   512, 0, 3, 9999, 0, pe_w);
      attn_mfma<<<128, 256, 0, stream>>>(qkvh, qkvl, Vth, Vtl, xch, xcl);
      gemm_hl<<<dim3(8, 16, 2), 256, 0, stream>>>(xch, xcl, 512, wh + wbase + 786432,
                                                  wl + wbase + 786432, 512,
                                                  bo, bo, bo, bD, bD, bD, 9,
                                                  x, nullptr, nullptr, nullptr, nullptr, 512,
                                                  512, 0, 1, 9999, 0, pe_w);
      ln2<<<1024, 256, 0, stream>>>(x, nullptr, xch, xcl, lnin_w, lnin_b, bD, pe_w);
      gemm_hl<<<dim3(32, 16, 1), 256, 0, stream>>>(xch, xcl, 512, wh + wbase + 1048576,
                                                   wl + wbase + 1048576, 512,
                                                   ff1b, ff1b, ff1b,
                                                   (size_t)l * DFF, (size_t)l * DFF, (size_t)l * DFF, 11,
                                                   nullptr, ffch, ffcl, nullptr, nullptr, 2048,
                                                   512, 1, 2, 9999, 0, pe_w);
      gemm_hl<<<dim3(8, 16, 2), 256, 0, stream>>>(ffch, ffcl, 2048, wh + wbase + 2097152,
                                                  wl + wbase + 2097152, 2048,
                                                  ff2b, ff2b, ff2b, bD, bD, bD, 9,
                                                  x, nullptr, nullptr, nullptr, nullptr, 512,
                                                  2048, 0, 1, 9999, 0, pe_w);
      ln2<<<1024, 256, 0, stream>>>(x, x, xch, xcl, lnout_w, lnout_b, bD, pe_w);
    }

    // Sim head
    gemm_hl<<<dim3(8, 16, 1), 256, 0, stream>>>(xch, xcl, 512, wh + 12582912, wl + 12582912, 512,
                                                simbq, simbk, simbk, 0, 0, 0, 9,
                                                qkb, qsh, qsl, nullptr, nullptr, 512,
                                                512, 0, 4, 8, 512, pe_w);
    projgram<<<1049, 64, 0, stream>>>(qkb, ce, ck, Gbuf, pe_w);
    sim_mid<<<80, 256, 0, stream>>>(aqr, qa, ck, Gbuf, qsh, qsl, R, Sbuf, pe_w);
    softmax_rel<<<512, 128, 0, stream>>>(Sbuf, R, PT);
    pbar2<<<512, 64, 0, stream>>>(PT, aqr, Pbar, pabarS, pe_w);
    meancls<<<4, 512, 0, stream>>>(qkb, Pbar, pabarS, ce, clsw, clsb, d_out, pe_w);
    return;
  }

  // -------- FALLBACK: round-6 passing path --------
  float* ws = (float*)d_ws;
  const size_t S = (size_t)512 * 512;
  float* qe = ws;
  float* ae = ws + S;
  float* hb = ws + 2 * S;
  float* rb = ws + 3 * S;
  float* qb = rb;
  float* kb = rb + S;
  float* vb = rb + 2 * S;
  float* ob = rb + 3 * S;
  float* ffb = rb;
  float* pbuf = rb + 2 * S;
  float* pabuf = pbuf + 65536;
  float* qcbuf = pabuf + 2560;
  float* kcbuf = qcbuf + 2560;
  float* Gbuf = kcbuf + 2560;
  float* xmean = Gbuf + 32;
  float* xsim = rb + 3 * S;
  int* dflag = (int*)(ws + 7 * S);

  const int M = B * T;
  dim3 gD(8, 8), gF1(32, 8), gF2(8, 8);

  flag_kernel<<<1, 64, 0, stream>>>(pe_w, dflag);
  for (int e = 0; e < 2; ++e) {
    float* x = (e == 0) ? qe : ae;
    const void* emb = (e == 0) ? q_emb : a_emb;
    emb_ln_kernel<<<M, 256, 0, stream>>>(emb, pos, pe_w, pe_b, x, T, D, dflag);
    for (int l = 0; l < NL; ++l) {
      size_t wDD = (size_t)l * D * D, bD = (size_t)l * D;
      gemm_mfma<<<gD, 256, 0, stream>>>(x, Wq, wDD, bq, bD, qb, M, D, D, 0, 0, dflag);
      gemm_mfma<<<gD, 256, 0, stream>>>(x, Wk, wDD, bk, bD, kb, M, D, D, 0, 0, dflag);
      gemm_mfma<<<gD, 256, 0, stream>>>(x, Wv, wDD, bv, bD, vb, M, D, D, 0, 0, dflag);
      attn_kernel<<<B * H * T, 128, 0, stream>>>(qb, kb, vb, ob, B, H, T, D / H);
      gemm_mfma<<<gD, 256, 0, stream>>>(ob, Wo, wDD, bo, bD, x, M, D, D, 0, 1, dflag);
      ln_kernel<<<M, 256, 0, stream>>>(x, hb, lnin_w, lnin_b, bD, D, dflag);
      gemm_mfma<<<gF1, 256, 0, stream>>>(hb, ff1w, (size_t)l * D * DFF, ff1b, (size_t)l * DFF,
                                         ffb, M, DFF, D, 1, 0, dflag);
      gemm_mfma<<<gF2, 256, 0, stream>>>(ffb, ff2w, (size_t)l * DFF * D, ff2b, bD,
                                         x, M, D, DFF, 0, 1, dflag);
      ln_kernel<<<M, 256, 0, stream>>>(x, x, lnout_w, lnout_b, bD, D, dflag);
    }
  }
  gemm_mfma<<<gD, 256, 0, stream>>>(qe, simWq, 0, simbq, 0, qb, M, D, D, 0, 0, dflag);
  gemm_mfma<<<gD, 256, 0, stream>>>(ae, simWk, 0, simbk, 0, kb, M, D, D, 0, 0, dflag);
  proj_ce_kernel<<<M, 64, 0, stream>>>(qb, ce, qcbuf, D, NC, dflag);
  proj_ce_kernel<<<M, 64, 0, stream>>>(kb, ce, kcbuf, D, NC, dflag);
  gram_kernel<<<NC * NC, 64, 0, stream>>>(ce, Gbuf, D, NC, dflag);
  sim_scores_kernel<<<B * T, 128, 0, stream>>>(qb, kb, qa, aqr, qcbuf, kcbuf, Gbuf, pbuf, pabuf,
                                               B, T, T, D, NC, dflag);
  sim_x_kernel<<<B * T, 512, 0, stream>>>(pbuf, kb, pabuf, ce, xsim, B, T, T, D, NC, dflag);
  mean_kernel<<<B, 512, 0, stream>>>(xsim, xmean, T, D);
  cls_kernel<<<B * 3, 64, 0, stream>>>(xmean, clsw, clsb, d_out, D, 3, dflag);
}